// Round 12
// baseline (105.252 us; speedup 1.0000x reference)
//
#include <hip/hip_runtime.h>
#include <cstdint>
#include <cstddef>

typedef unsigned short u16;
typedef unsigned int u32;
typedef __attribute__((ext_vector_type(8))) short bf16x8;
typedef __attribute__((ext_vector_type(4))) float f32x4;

#define MFMA16(A, B, C) __builtin_amdgcn_mfma_f32_16x16x32_bf16((A), (B), (C), 0, 0, 0)

__device__ __forceinline__ u16 bf16_rne(float x) {
    u32 u = __float_as_uint(x);
    u += 0x7fffu + ((u >> 16) & 1u);
    return (u16)(u >> 16);
}
__device__ __forceinline__ float bf2f(u16 h) { return __uint_as_float((u32)h << 16); }
__device__ __forceinline__ u16 bf16_lo(float x, u16 hi) { return bf16_rne(x - bf2f(hi)); }
__device__ __forceinline__ float blo(u32 u) { return __uint_as_float(u << 16); }
__device__ __forceinline__ float bhi(u32 u) { return __uint_as_float(u & 0xffff0000u); }
// packed f32x2 -> bf16x2 (lo<-a, hi<-b), RNE
__device__ __forceinline__ u32 cvt_pk(float a, float b) {
    u32 r;
    asm("v_cvt_pk_bf16_f32 %0, %1, %2" : "=v"(r) : "v"(a), "v"(b));
    return r;
}

// ================= prep bodies =================
// B-frag (16x16x32): lane l, elem i holds B[k = 8*(l>>4)+i][col = 16*tile + (l&15)]
// (same bytes as A-frag give A[row=l&15][k=8*(l>>4)+i] -> operand-swap transposes C)
__device__ __forceinline__ void PK_body(int tid,
    const float* __restrict__ mpW1, const float* __restrict__ mpW2,
    const float* __restrict__ phW1, const float* __restrict__ phW2,
    const float* __restrict__ rhoW,
    u16* __restrict__ Bp1e, u16* __restrict__ Bp2e,
    u16* __restrict__ BpC1, u16* __restrict__ BpC2, u16* __restrict__ BpR)
{
    if (tid < 8192) {
        // edge L1: 16 tiles x 512, 4-group trick [w_hi, w_hi, w_lo, w_lo]
        int t = tid >> 9, r = tid & 511;
        int l = r >> 3, i = r & 7, g = l >> 4, l15 = l & 15;
        float w = mpW1[i * 256 + 16 * t + l15];
        u16 h = bf16_rne(w);
        Bp1e[tid] = (g < 2) ? h : bf16_lo(w, h);
    } else if (tid < 73728) {
        // edge L2: [(c*8+n)*2+s][512] from mpW2 (256x128)
        int f = tid - 8192;
        int b5 = f >> 9, r = f & 511;
        int l = r >> 3, i = r & 7, g = l >> 4, l15 = l & 15;
        int s = b5 & 1, cn = b5 >> 1, c = cn >> 3, n = cn & 7;
        int kk = 32 * c + 8 * g + i;
        float w = mpW2[kk * 128 + 16 * n + l15];
        u16 h = bf16_rne(w);
        Bp2e[f] = s ? bf16_lo(w, h) : h;
    } else if (tid < 155648) {
        // node L1: [(c*2+s)*16+t][512] from phW1 (153x256), K perm: 0..24 direct, 25..31 zero, 32..159 -> 25..152
        int f = tid - 73728;
        int b5 = f >> 9, r = f & 511;
        int l = r >> 3, i = r & 7, g = l >> 4, l15 = l & 15;
        int t = b5 & 15, cs = b5 >> 4, s = cs & 1, c = cs >> 1;
        int kk = 32 * c + 8 * g + i;
        int kp = kk < 25 ? kk : (kk < 32 ? -1 : kk - 7);
        float w = (kp < 0) ? 0.0f : phW1[kp * 256 + 16 * t + l15];
        u16 h = bf16_rne(w);
        BpC1[f] = s ? bf16_lo(w, h) : h;
    } else if (tid < 221184) {
        // node L2: from phW2 (256x128)
        int f = tid - 155648;
        int b5 = f >> 9, r = f & 511;
        int l = r >> 3, i = r & 7, g = l >> 4, l15 = l & 15;
        int s = b5 & 1, cn = b5 >> 1, c = cn >> 3, n = cn & 7;
        int kk = 32 * c + 8 * g + i;
        float w = phW2[kk * 128 + 16 * n + l15];
        u16 h = bf16_rne(w);
        BpC2[f] = s ? bf16_lo(w, h) : h;
    } else {
        // rho: [(c*16+t)*2+s][512] from rhoW (128x256)
        int f = tid - 221184;
        int b5 = f >> 9, r = f & 511;
        int l = r >> 3, i = r & 7, g = l >> 4, l15 = l & 15;
        int s = b5 & 1, ct = b5 >> 1, c = ct >> 4, t = ct & 15;
        int kk = 32 * c + 8 * g + i;
        float w = rhoW[kk * 256 + 16 * t + l15];
        u16 h = bf16_rne(w);
        BpR[f] = s ? bf16_lo(w, h) : h;
    }
}

// Ein[row][16] bf16 : [x_hi(8) | x_lo(8)]  (GF reconstructs the 4-group via gq&1)
__device__ __forceinline__ void P1_body(int row,
    const float* __restrict__ obs, const float* __restrict__ ag, const float* __restrict__ g,
    const int* __restrict__ src, const int* __restrict__ dst, const int* __restrict__ pred,
    u16* __restrict__ Ein)
{
    int b = row / 20, p = row - b * 20;
    float inp[8];
    int i0 = pred[2 * p], i1 = pred[2 * p + 1];
    const float* gb = g + (size_t)b * 40;
    const float* ab = ag + (size_t)b * 40;
    inp[0] = gb[i0] - ab[i0];
    inp[1] = gb[i1] - ab[i1];
    int so = src[p], dd = dst[p];
    const float* ob = obs + (size_t)b * 85 + 10;
    inp[2] = ob[so * 15 + 0]; inp[3] = ob[so * 15 + 1]; inp[4] = ob[so * 15 + 2];
    inp[5] = ob[dd * 15 + 0]; inp[6] = ob[dd * 15 + 1]; inp[7] = ob[dd * 15 + 2];

    u32 wh[4], wl[4];
    #pragma unroll
    for (int k = 0; k < 4; ++k) {
        u16 h0 = bf16_rne(inp[2 * k]), h1 = bf16_rne(inp[2 * k + 1]);
        u16 l0 = bf16_lo(inp[2 * k], h0), l1 = bf16_lo(inp[2 * k + 1], h1);
        wh[k] = (u32)h0 | ((u32)h1 << 16);
        wl[k] = (u32)l0 | ((u32)l1 << 16);
    }
    uint4* d4 = (uint4*)(Ein + (size_t)row * 16);
    d4[0] = make_uint4(wh[0], wh[1], wh[2], wh[3]);
    d4[1] = make_uint4(wl[0], wl[1], wl[2], wl[3]);
}

// ================= PREP: PK + P1 + headWpk fused =================
__global__ __launch_bounds__(256) void PREP(
    const float* __restrict__ mpW1, const float* __restrict__ mpW2,
    const float* __restrict__ phW1, const float* __restrict__ phW2,
    const float* __restrict__ rhoW,
    u16* __restrict__ Bp1e, u16* __restrict__ Bp2e,
    u16* __restrict__ BpC1, u16* __restrict__ BpC2, u16* __restrict__ BpR,
    const float* __restrict__ obs, const float* __restrict__ ag, const float* __restrict__ g,
    const int* __restrict__ src, const int* __restrict__ dst, const int* __restrict__ pred,
    u16* __restrict__ Ein,
    const float* __restrict__ meanW, const float* __restrict__ lsW,
    float* __restrict__ headWpk)
{
    int bid = blockIdx.x;
    if (bid < 1120) {
        PK_body(bid * 256 + threadIdx.x, mpW1, mpW2, phW1, phW2, rhoW, Bp1e, Bp2e, BpC1, BpC2, BpR);
    } else if (bid < 2400) {
        P1_body((bid - 1120) * 256 + threadIdx.x, obs, ag, g, src, dst, pred, Ein);
    } else {
        // headWpk f32[256][8]: q<4 mean, q>=4 logstd
        int idx = threadIdx.x;
        #pragma unroll
        for (int r = 0; r < 8; ++r) {
            int f = r * 256 + idx;
            int k = f >> 3, q = f & 7;
            headWpk[f] = (q < 4) ? meanW[k * 4 + q] : lsW[k * 4 + (q - 4)];
        }
    }
}

// ================= GF: fully fused edge MLP + aggregate + node MLP + pool + rho + heads =================
// 1024 blocks x 512 threads; 16 batches per block.
// Edge phase: 4 groups x {80 edge rows main loop (R11 3-buffer schedule) + aggregate tail -> Nin rows in LDS}.
// Node phase: proven R10/R11 node body reading Nin from LDS, writing only d_out.
__global__ __launch_bounds__(512) void GF(
    const u16* __restrict__ Ein, const u16* __restrict__ Bp1, const u16* __restrict__ Bp2,
    const float* __restrict__ eb1, const float* __restrict__ eb2,
    const float* __restrict__ eaW, const float* __restrict__ eab,
    const int* __restrict__ inc, const float* __restrict__ obs,
    const u16* __restrict__ BpC1, const u16* __restrict__ BpC2, const u16* __restrict__ BpR,
    const float* __restrict__ nb1, const float* __restrict__ nb2,
    const float* __restrict__ saW, const float* __restrict__ sab,
    const float* __restrict__ rhob, const float* __restrict__ headWpk,
    const float* __restrict__ meanb, const float* __restrict__ lsb,
    float* __restrict__ outp)
{
    // LDS arena, explicit offsets (total 76176 B -> 2 blocks/CU):
    //  [0,     24576)  hb: 3 x 8192 h-tile buffers (edge AND node), swizzled
    //  [24576, 45696)  M: edge mpb 80x128 u16 swizzled (20480) / node phibuf 80x132 u16 (21120) / rbuf f32 stride 260 (16640)
    //  [45696, 72576)  NinL: 80 rows x 168 u16 (336 B stride; 84 banks/row => 2-way-free reads)
    //  [72576, 75136)  spart[8][80] f32 (edge & node, phase-sequential) / hpart[512]
    //  [75136, 75456)  wbuf[80]
    //  [75456, 75776)  awb[80]
    //  [75776, 76096)  rowb[80]
    //  [76096, 76176)  incL[20]
    __shared__ __align__(16) char S[76176];
    const int tid = threadIdx.x;
    const int w = tid >> 6, lane = tid & 63;
    const int l15 = lane & 15, gq = lane >> 4;
    char* hbc = S;
    char* mpc = S + 24576;
    char* ninc = S + 45696;
    float* spart = (float*)(S + 72576);
    float* wbuf = (float*)(S + 75136);
    float* awb  = (float*)(S + 75456);
    int*   rowb = (int*)(S + 75776);
    int*   incL = (int*)(S + 76096);

    if (tid < 20) incL[tid] = inc[tid];

    // =================== EDGE PHASE ===================
    {
        // edge stage-1 W-frags (tiles 2w,2w+1; exact 4-group hi/lo) + per-col biases
        bf16x8 B1[2];
        float4 b1v[2];
        #pragma unroll
        for (int t = 0; t < 2; ++t) {
            B1[t] = *(const bf16x8*)(Bp1 + (size_t)(2 * w + t) * 512 + lane * 8);
            b1v[t] = *(const float4*)(eb1 + 16 * (2 * w + t) + 4 * gq);
        }
        // edge stage-2 W-frags (tile n=w), hi only
        bf16x8 B2[8];
        #pragma unroll
        for (int c = 0; c < 8; ++c)
            B2[c] = *(const bf16x8*)(Bp2 + (size_t)((c * 8 + w) * 2) * 512 + lane * 8);
        const float4 b2v = *(const float4*)(eb2 + 16 * w + 4 * gq);
        const float4 eav = *(const float4*)(eaW + 16 * w + 4 * gq);

        auto stage1e = [&](int buf, const bf16x8& X) {
            #pragma unroll
            for (int t = 0; t < 2; ++t) {
                f32x4 acc = {b1v[t].x, b1v[t].y, b1v[t].z, b1v[t].w};
                acc = MFMA16(B1[t], X, acc);   // swapped: C[m=col][n=row]
                u32 p0 = cvt_pk(fmaxf(acc[0], 0.f), fmaxf(acc[1], 0.f));
                u32 p1 = cvt_pk(fmaxf(acc[2], 0.f), fmaxf(acc[3], 0.f));
                int colu = 16 * (2 * w + t) + 4 * gq;
                int byte = buf * 8192 + ((l15 * 512 + colu * 2) ^ ((l15 & 7) << 4));
                *(uint2*)(hbc + byte) = make_uint2(p0, p1);
            }
        };
        auto stage2e = [&](int m, int buf) {
            f32x4 accA = {b2v.x, b2v.y, b2v.z, b2v.w};
            f32x4 accB = {0.f, 0.f, 0.f, 0.f};
            #pragma unroll
            for (int c = 0; c < 4; ++c) {
                int byteA = buf * 8192 + ((l15 * 512 + (2 * c) * 64 + gq * 16) ^ ((l15 & 7) << 4));
                int byteB = buf * 8192 + ((l15 * 512 + (2 * c + 1) * 64 + gq * 16) ^ ((l15 & 7) << 4));
                const bf16x8 HA = *(const bf16x8*)(hbc + byteA);
                const bf16x8 HB = *(const bf16x8*)(hbc + byteB);
                accA = MFMA16(B2[2 * c], HA, accA);
                accB = MFMA16(B2[2 * c + 1], HB, accB);
            }
            float v0 = fmaxf(accA[0] + accB[0], 0.f), v1 = fmaxf(accA[1] + accB[1], 0.f);
            float v2 = fmaxf(accA[2] + accB[2], 0.f), v3 = fmaxf(accA[3] + accB[3], 0.f);
            float ep = v0 * eav.x + v1 * eav.y + v2 * eav.z + v3 * eav.w;
            ep += __shfl_xor(ep, 16, 64);
            ep += __shfl_xor(ep, 32, 64);
            if (gq == 0) spart[w * 80 + m * 16 + l15] = ep;
            u32 p0 = cvt_pk(v0, v1), p1 = cvt_pk(v2, v3);
            int r = m * 16 + l15;
            int byte2 = (r * 256 + (16 * w + 4 * gq) * 2) ^ ((r & 15) << 4);
            *(uint2*)(mpc + byte2) = make_uint2(p0, p1);
        };

        #pragma unroll 1
        for (int g = 0; g < 4; ++g) {
            const int rowbaseE = blockIdx.x * 320 + g * 80;
            auto ldX = [&](int m) {
                return *(const bf16x8*)(Ein + (size_t)(rowbaseE + m * 16 + l15) * 16 + 8 * (gq & 1));
            };
            // prologue: fill hb0,hb1 (m=0,1)
            {
                bf16x8 X0 = ldX(0);
                bf16x8 X1 = ldX(1);
                stage1e(0, X0);
                stage1e(1, X1);
            }
            __syncthreads();
            // I0: compute m=0,1; fill hb2 <- m=2
            {
                bf16x8 X2 = ldX(2);
                stage2e(0, 0);
                stage2e(1, 1);
                stage1e(2, X2);
            }
            __syncthreads();
            // I1: compute m=2; fill hb0 <- m=3, hb1 <- m=4
            {
                bf16x8 X3 = ldX(3);
                bf16x8 X4 = ldX(4);
                stage2e(2, 2);
                stage1e(0, X3);
                stage1e(1, X4);
            }
            __syncthreads();
            // I2: compute m=3,4
            stage2e(3, 0);
            stage2e(4, 1);
            __syncthreads();

            // ---- tail: softmax weights (tid<20) || NinL cols 0..31 (tid 320..479) ----
            if (tid < 20) {
                int bl = tid / 5, o = tid - bl * 5;
                const float e0 = eab[0];
                int rr[4]; float ee[4];
                #pragma unroll
                for (int i = 0; i < 4; ++i) {
                    rr[i] = bl * 20 + incL[o * 4 + i];
                    float e = e0;
                    #pragma unroll
                    for (int ww = 0; ww < 8; ++ww) e += spart[ww * 80 + rr[i]];
                    ee[i] = e;
                }
                float mx = fmaxf(fmaxf(ee[0], ee[1]), fmaxf(ee[2], ee[3]));
                float ex[4]; float den = 0.f;
                #pragma unroll
                for (int i = 0; i < 4; ++i) { ex[i] = __expf(ee[i] - mx); den += ex[i]; }
                float inv = 1.0f / den;
                #pragma unroll
                for (int i = 0; i < 4; ++i) {
                    wbuf[tid * 4 + i] = ex[i] * inv;
                    rowb[tid * 4 + i] = rr[i];
                }
            } else if (tid >= 320 && tid < 480) {
                int t2 = tid - 320;
                int p = t2 >> 3, q = t2 & 7;
                int bl = p / 5, o = p - bl * 5;
                const float* body = obs + (size_t)(blockIdx.x * 16 + g * 4 + bl) * 85;
                const float* op = body + 10 + o * 15;
                float v[4];
                #pragma unroll
                for (int jj = 0; jj < 4; ++jj) {
                    int col = 4 * q + jj;
                    v[jj] = (col < 10) ? body[col] : (col < 25) ? op[col - 10] : 0.0f;
                }
                *(uint2*)(ninc + (size_t)(g * 20 + p) * 336 + q * 8) =
                    make_uint2(cvt_pk(v[0], v[1]), cvt_pk(v[2], v[3]));
            }
            __syncthreads();

            // ---- weighted gather -> NinL cols 32..159 ----
            if (tid < 320) {
                int p = tid >> 4, cb = tid & 15;
                float acc[8] = {0, 0, 0, 0, 0, 0, 0, 0};
                #pragma unroll
                for (int i = 0; i < 4; ++i) {
                    int r = rowb[p * 4 + i];
                    float wi = wbuf[p * 4 + i];
                    int byte = (r * 256 + cb * 16) ^ ((r & 15) << 4);
                    uint4 v = *(const uint4*)(mpc + byte);
                    acc[0] = fmaf(wi, blo(v.x), acc[0]);
                    acc[1] = fmaf(wi, bhi(v.x), acc[1]);
                    acc[2] = fmaf(wi, blo(v.y), acc[2]);
                    acc[3] = fmaf(wi, bhi(v.y), acc[3]);
                    acc[4] = fmaf(wi, blo(v.z), acc[4]);
                    acc[5] = fmaf(wi, bhi(v.z), acc[5]);
                    acc[6] = fmaf(wi, blo(v.w), acc[6]);
                    acc[7] = fmaf(wi, bhi(v.w), acc[7]);
                }
                uint4 ov;
                ov.x = cvt_pk(acc[0], acc[1]);
                ov.y = cvt_pk(acc[2], acc[3]);
                ov.z = cvt_pk(acc[4], acc[5]);
                ov.w = cvt_pk(acc[6], acc[7]);
                *(uint4*)(ninc + (size_t)(g * 20 + p) * 336 + 64 + cb * 16) = ov;
            }
            __syncthreads();
        }
    }

    // pin node-weight loads below the edge phase (keep peak VGPR <= ~128)
    __builtin_amdgcn_sched_barrier(0);

    // =================== NODE PHASE ===================
    {
        float* rbuf = (float*)mpc;           // f32 stride 260 (aliases phibuf region after pooling)
        float* hpart = spart;
        u32* poolw = (u32*)hbc;              // aliases dead hb after node main loop

        // node stage-1 W-frags: 5 chunks x 2 tiles, hi only + per-col bias (RESIDENT)
        bf16x8 BC[5][2];
        float4 b1v[2];
        #pragma unroll
        for (int t = 0; t < 2; ++t) b1v[t] = *(const float4*)(nb1 + 16 * (2 * w + t) + 4 * gq);
        #pragma unroll
        for (int c = 0; c < 5; ++c)
            #pragma unroll
            for (int t = 0; t < 2; ++t)
                BC[c][t] = *(const bf16x8*)(BpC1 + (size_t)((c * 2) * 16 + 2 * w + t) * 512 + lane * 8);
        // node stage-2 W-frags, hi only (RESIDENT)
        bf16x8 B2[8];
        #pragma unroll
        for (int c = 0; c < 8; ++c)
            B2[c] = *(const bf16x8*)(BpC2 + (size_t)((c * 8 + w) * 2) * 512 + lane * 8);
        const float4 b2v = *(const float4*)(nb2 + 16 * w + 4 * gq);
        const float4 sav = *(const float4*)(saW + 16 * w + 4 * gq);

        auto loadX = [&](int m, bf16x8* X) {
            #pragma unroll
            for (int c = 0; c < 5; ++c)
                X[c] = *(const bf16x8*)(ninc + (size_t)(m * 16 + l15) * 336 + c * 64 + gq * 16);
        };
        auto stage1n = [&](int buf, const bf16x8* X) {
            f32x4 a0 = {b1v[0].x, b1v[0].y, b1v[0].z, b1v[0].w};
            f32x4 a1 = {b1v[1].x, b1v[1].y, b1v[1].z, b1v[1].w};
            #pragma unroll
            for (int c = 0; c < 5; ++c) {
                a0 = MFMA16(BC[c][0], X[c], a0);
                a1 = MFMA16(BC[c][1], X[c], a1);
            }
            #pragma unroll
            for (int t = 0; t < 2; ++t) {
                const f32x4& a = t ? a1 : a0;
                u32 p0 = cvt_pk(fmaxf(a[0], 0.f), fmaxf(a[1], 0.f));
                u32 p1 = cvt_pk(fmaxf(a[2], 0.f), fmaxf(a[3], 0.f));
                int colu = 16 * (2 * w + t) + 4 * gq;
                int byte = buf * 8192 + ((l15 * 512 + colu * 2) ^ ((l15 & 7) << 4));
                *(uint2*)(hbc + byte) = make_uint2(p0, p1);
            }
        };
        auto stage2n = [&](int m, int buf) {
            f32x4 accA = {b2v.x, b2v.y, b2v.z, b2v.w};
            f32x4 accB = {0.f, 0.f, 0.f, 0.f};
            #pragma unroll
            for (int c = 0; c < 4; ++c) {
                int byteA = buf * 8192 + ((l15 * 512 + (2 * c) * 64 + gq * 16) ^ ((l15 & 7) << 4));
                int byteB = buf * 8192 + ((l15 * 512 + (2 * c + 1) * 64 + gq * 16) ^ ((l15 & 7) << 4));
                const bf16x8 HA = *(const bf16x8*)(hbc + byteA);
                const bf16x8 HB = *(const bf16x8*)(hbc + byteB);
                accA = MFMA16(B2[2 * c], HA, accA);
                accB = MFMA16(B2[2 * c + 1], HB, accB);
            }
            float v0 = fmaxf(accA[0] + accB[0], 0.f), v1 = fmaxf(accA[1] + accB[1], 0.f);
            float v2 = fmaxf(accA[2] + accB[2], 0.f), v3 = fmaxf(accA[3] + accB[3], 0.f);
            int r = m * 16 + l15;
            *(uint2*)(mpc + r * 264 + (16 * w + 4 * gq) * 2) =
                make_uint2(cvt_pk(v0, v1), cvt_pk(v2, v3));
            float sp = v0 * sav.x + v1 * sav.y + v2 * sav.z + v3 * sav.w;
            sp += __shfl_xor(sp, 16, 64);
            sp += __shfl_xor(sp, 32, 64);
            if (gq == 0) spart[w * 80 + r] = sp;
        };

        // prologue: fill hb0,hb1 (m=0,1)
        {
            bf16x8 X0[5], X1[5];
            loadX(0, X0);
            loadX(1, X1);
            stage1n(0, X0);
            stage1n(1, X1);
        }
        __syncthreads();
        // I0: compute m=0,1; fill hb2 <- m=2
        {
            bf16x8 X2[5];
            loadX(2, X2);
            stage2n(0, 0);
            stage2n(1, 1);
            stage1n(2, X2);
        }
        __syncthreads();
        // I1: compute m=2; fill hb0 <- m=3, hb1 <- m=4
        {
            bf16x8 X3[5], X4[5];
            loadX(3, X3);
            loadX(4, X4);
            stage2n(2, 2);
            stage1n(0, X3);
            stage1n(1, X4);
        }
        __syncthreads();
        // I2: compute m=3,4
        stage2n(3, 0);
        stage2n(4, 1);
        __syncthreads();

        // ---- softmax over 5 objects per batch ----
        if (tid < 16) {
            const float s0c = sab[0];
            float ss[5];
            #pragma unroll
            for (int o = 0; o < 5; ++o) {
                float s = s0c;
                #pragma unroll
                for (int ww = 0; ww < 8; ++ww) s += spart[ww * 80 + tid * 5 + o];
                ss[o] = s;
            }
            float mx = fmaxf(fmaxf(fmaxf(ss[0], ss[1]), fmaxf(ss[2], ss[3])), ss[4]);
            float ex[5]; float den = 0.f;
            #pragma unroll
            for (int o = 0; o < 5; ++o) { ex[o] = __expf(ss[o] - mx); den += ex[o]; }
            float inv = 1.0f / den;
            #pragma unroll
            for (int o = 0; o < 5; ++o) awb[tid * 5 + o] = ex[o] * inv;
        }
        __syncthreads();

        // ---- pooling: 1024 u32 words (2 cols each) -> poolw (aliases dead hb) ----
        #pragma unroll
        for (int rep = 0; rep < 2; ++rep) {
            int idx = rep * 512 + tid;       // < 1024
            int b = idx >> 6, cw = idx & 63;
            float p0 = 0.f, p1 = 0.f;
            #pragma unroll
            for (int o = 0; o < 5; ++o) {
                u32 v = *(const u32*)(mpc + (size_t)(b * 5 + o) * 264 + cw * 4);
                float a = awb[b * 5 + o];
                p0 = fmaf(a, blo(v), p0);
                p1 = fmaf(a, bhi(v), p1);
            }
            u16 h0 = bf16_rne(p0); u16 l0 = bf16_lo(p0, h0);
            u16 h1 = bf16_rne(p1); u16 l1 = bf16_lo(p1, h1);
            *(uint2*)(poolw + b * 132 + 2 * cw) =
                make_uint2((u32)h0 | ((u32)l0 << 16), (u32)h1 | ((u32)l1 << 16));
        }
        __syncthreads();   // phibuf dead; rbuf may overwrite

        // ---- rho (swapped): A = pooled hi+lo, B = rhoW hi only ----
        {
            float4 rb0 = *(const float4*)(rhob + 16 * (2 * w + 0) + 4 * gq);
            float4 rb1 = *(const float4*)(rhob + 16 * (2 * w + 1) + 4 * gq);
            f32x4 acc0 = {rb0.x, rb0.y, rb0.z, rb0.w};
            f32x4 acc1 = {rb1.x, rb1.y, rb1.z, rb1.w};
            #pragma unroll
            for (int c = 0; c < 4; ++c) {
                uint4 q0 = *(const uint4*)(poolw + l15 * 132 + 32 * c + 8 * gq);
                uint4 q1 = *(const uint4*)(poolw + l15 * 132 + 32 * c + 8 * gq + 4);
                u32 ws[8] = {q0.x, q0.y, q0.z, q0.w, q1.x, q1.y, q1.z, q1.w};
                bf16x8 Ph, Pl;
                #pragma unroll
                for (int i = 0; i < 8; ++i) {
                    Ph[i] = (short)(ws[i] & 0xffffu);
                    Pl[i] = (short)(ws[i] >> 16);
                }
                #pragma unroll
                for (int t = 0; t < 2; ++t) {
                    bf16x8 Bh = *(const bf16x8*)(BpR + (size_t)((c * 16 + 2 * w + t) * 2 + 0) * 512 + lane * 8);
                    f32x4& a = t ? acc1 : acc0;
                    a = MFMA16(Bh, Ph, a);
                    a = MFMA16(Bh, Pl, a);
                }
            }
            #pragma unroll
            for (int t = 0; t < 2; ++t) {
                const f32x4& a = t ? acc1 : acc0;
                float4 v;
                v.x = fmaxf(a[0], 0.f); v.y = fmaxf(a[1], 0.f);
                v.z = fmaxf(a[2], 0.f); v.w = fmaxf(a[3], 0.f);
                *(float4*)(rbuf + l15 * 260 + 16 * (2 * w + t) + 4 * gq) = v;
            }
        }
        __syncthreads();

        // ---- heads split-k: 512 threads = 4 k-splits x (16 b x 8 q) ----
        {
            int s = tid >> 7, p = tid & 127;
            int b = p >> 3, q = p & 7;
            const float* rrow = rbuf + b * 260 + s * 64;
            const float* wcol = headWpk + s * 64 * 8 + q;
            float acc = 0.f;
            #pragma unroll 8
            for (int k = 0; k < 64; ++k)
                acc = fmaf(rrow[k], wcol[k * 8], acc);
            hpart[s * 128 + p] = acc;
        }
        __syncthreads();
        if (tid < 128) {
            int b = tid >> 3, q = tid & 7;
            float a = hpart[tid] + hpart[128 + tid] + hpart[256 + tid] + hpart[384 + tid];
            int bg = blockIdx.x * 16 + b;
            if (q < 4) {
                outp[(size_t)bg * 4 + q] = a + meanb[q];
            } else {
                float l = a + lsb[q - 4];
                outp[65536 + (size_t)bg * 4 + (q - 4)] = fminf(fmaxf(l, -20.0f), 2.0f);
            }
        }
    }
}

extern "C" void kernel_launch(void* const* d_in, const int* in_sizes, int n_in,
                              void* d_out, int out_size, void* d_ws, size_t ws_size,
                              hipStream_t stream)
{
    const float* obs   = (const float*)d_in[0];
    const float* ag    = (const float*)d_in[1];
    const float* g     = (const float*)d_in[2];
    const float* mpW1  = (const float*)d_in[3];
    const float* mpb1  = (const float*)d_in[4];
    const float* mpW2  = (const float*)d_in[5];
    const float* mpb2  = (const float*)d_in[6];
    const float* eaW   = (const float*)d_in[7];
    const float* eab   = (const float*)d_in[8];
    const float* phW1  = (const float*)d_in[9];
    const float* phb1  = (const float*)d_in[10];
    const float* phW2  = (const float*)d_in[11];
    const float* phb2  = (const float*)d_in[12];
    const float* saW   = (const float*)d_in[13];
    const float* sab   = (const float*)d_in[14];
    const float* rhoW  = (const float*)d_in[15];
    const float* rhob  = (const float*)d_in[16];
    const float* meanW = (const float*)d_in[17];
    const float* meanb = (const float*)d_in[18];
    const float* lsW   = (const float*)d_in[19];
    const float* lsb   = (const float*)d_in[20];
    const int*   src   = (const int*)d_in[21];
    const int*   dst   = (const int*)d_in[22];
    const int*   inc   = (const int*)d_in[23];
    const int*   pred  = (const int*)d_in[24];

    // workspace layout (bytes):
    //  Ein  (u16 327680x16) : [0, 10485760)
    //  Bp1e (u16 8192)      : [36700160, +16384)
    //  Bp2e (u16 65536)     : [36716544, +131072)
    //  BpC1 (u16 81920)     : [36847616, +163840)
    //  BpC2 (u16 65536)     : [37011456, +131072)
    //  BpR  (u16 65536)     : [37142528, +131072)
    //  headWpk (f32 2048)   : [37273600, +8192)
    char* ws = (char*)d_ws;
    u16* Ein  = (u16*)(ws + 0);
    u16* Bp1e = (u16*)(ws + 36700160ull);
    u16* Bp2e = (u16*)(ws + 36716544ull);
    u16* BpC1 = (u16*)(ws + 36847616ull);
    u16* BpC2 = (u16*)(ws + 37011456ull);
    u16* BpR  = (u16*)(ws + 37142528ull);
    float* headWpk = (float*)(ws + 37273600ull);

    hipLaunchKernelGGL(PREP, dim3(2401), dim3(256), 0, stream,
                       mpW1, mpW2, phW1, phW2, rhoW, Bp1e, Bp2e, BpC1, BpC2, BpR,
                       obs, ag, g, src, dst, pred, Ein, meanW, lsW, headWpk);
    hipLaunchKernelGGL(GF, dim3(1024), dim3(512), 0, stream,
                       Ein, Bp1e, Bp2e, mpb1, mpb2, eaW, eab, inc, obs,
                       BpC1, BpC2, BpR, phb1, phb2, saW, sab, rhob,
                       headWpk, meanb, lsb, (float*)d_out);
}

// Round 13
// 101.705 us; speedup vs baseline: 1.0349x; 1.0349x over previous
//
#include <hip/hip_runtime.h>
#include <cstdint>
#include <cstddef>

typedef unsigned short u16;
typedef unsigned int u32;
typedef __attribute__((ext_vector_type(8))) short bf16x8;
typedef __attribute__((ext_vector_type(4))) float f32x4;

#define MFMA16(A, B, C) __builtin_amdgcn_mfma_f32_16x16x32_bf16((A), (B), (C), 0, 0, 0)

__device__ __forceinline__ u16 bf16_rne(float x) {
    u32 u = __float_as_uint(x);
    u += 0x7fffu + ((u >> 16) & 1u);
    return (u16)(u >> 16);
}
__device__ __forceinline__ float bf2f(u16 h) { return __uint_as_float((u32)h << 16); }
__device__ __forceinline__ u16 bf16_lo(float x, u16 hi) { return bf16_rne(x - bf2f(hi)); }
__device__ __forceinline__ float blo(u32 u) { return __uint_as_float(u << 16); }
__device__ __forceinline__ float bhi(u32 u) { return __uint_as_float(u & 0xffff0000u); }
// packed f32x2 -> bf16x2 (lo<-a, hi<-b), RNE
__device__ __forceinline__ u32 cvt_pk(float a, float b) {
    u32 r;
    asm("v_cvt_pk_bf16_f32 %0, %1, %2" : "=v"(r) : "v"(a), "v"(b));
    return r;
}

// ================= prep: weight packing =================
// B-frag (16x16x32): lane l, elem i holds B[k = 8*(l>>4)+i][col = 16*tile + (l&15)]
// (same bytes as A-frag give A[row=l&15][k=8*(l>>4)+i] -> operand-swap transposes C)
__device__ __forceinline__ void PK_body(int tid,
    const float* __restrict__ mpW1, const float* __restrict__ mpW2,
    const float* __restrict__ phW1, const float* __restrict__ phW2,
    const float* __restrict__ rhoW,
    u16* __restrict__ Bp1e, u16* __restrict__ Bp2e,
    u16* __restrict__ BpC1, u16* __restrict__ BpC2, u16* __restrict__ BpR)
{
    if (tid < 8192) {
        // edge L1: 16 tiles x 512, 4-group trick [w_hi, w_hi, w_lo, w_lo]
        int t = tid >> 9, r = tid & 511;
        int l = r >> 3, i = r & 7, g = l >> 4, l15 = l & 15;
        float w = mpW1[i * 256 + 16 * t + l15];
        u16 h = bf16_rne(w);
        Bp1e[tid] = (g < 2) ? h : bf16_lo(w, h);
    } else if (tid < 73728) {
        // edge L2: [(c*8+n)*2+s][512] from mpW2 (256x128)
        int f = tid - 8192;
        int b5 = f >> 9, r = f & 511;
        int l = r >> 3, i = r & 7, g = l >> 4, l15 = l & 15;
        int s = b5 & 1, cn = b5 >> 1, c = cn >> 3, n = cn & 7;
        int kk = 32 * c + 8 * g + i;
        float w = mpW2[kk * 128 + 16 * n + l15];
        u16 h = bf16_rne(w);
        Bp2e[f] = s ? bf16_lo(w, h) : h;
    } else if (tid < 155648) {
        // node L1: [(c*2+s)*16+t][512] from phW1 (153x256), K perm: 0..24 direct, 25..31 zero, 32..159 -> 25..152
        int f = tid - 73728;
        int b5 = f >> 9, r = f & 511;
        int l = r >> 3, i = r & 7, g = l >> 4, l15 = l & 15;
        int t = b5 & 15, cs = b5 >> 4, s = cs & 1, c = cs >> 1;
        int kk = 32 * c + 8 * g + i;
        int kp = kk < 25 ? kk : (kk < 32 ? -1 : kk - 7);
        float w = (kp < 0) ? 0.0f : phW1[kp * 256 + 16 * t + l15];
        u16 h = bf16_rne(w);
        BpC1[f] = s ? bf16_lo(w, h) : h;
    } else if (tid < 221184) {
        // node L2: from phW2 (256x128)
        int f = tid - 155648;
        int b5 = f >> 9, r = f & 511;
        int l = r >> 3, i = r & 7, g = l >> 4, l15 = l & 15;
        int s = b5 & 1, cn = b5 >> 1, c = cn >> 3, n = cn & 7;
        int kk = 32 * c + 8 * g + i;
        float w = phW2[kk * 128 + 16 * n + l15];
        u16 h = bf16_rne(w);
        BpC2[f] = s ? bf16_lo(w, h) : h;
    } else {
        // rho: [(c*16+t)*2+s][512] from rhoW (128x256)
        int f = tid - 221184;
        int b5 = f >> 9, r = f & 511;
        int l = r >> 3, i = r & 7, g = l >> 4, l15 = l & 15;
        int s = b5 & 1, ct = b5 >> 1, c = ct >> 4, t = ct & 15;
        int kk = 32 * c + 8 * g + i;
        float w = rhoW[kk * 256 + 16 * t + l15];
        u16 h = bf16_rne(w);
        BpR[f] = s ? bf16_lo(w, h) : h;
    }
}

// ================= PREP: PK + headWpk (P1 now inlined in GA) =================
__global__ __launch_bounds__(256) void PREP(
    const float* __restrict__ mpW1, const float* __restrict__ mpW2,
    const float* __restrict__ phW1, const float* __restrict__ phW2,
    const float* __restrict__ rhoW,
    u16* __restrict__ Bp1e, u16* __restrict__ Bp2e,
    u16* __restrict__ BpC1, u16* __restrict__ BpC2, u16* __restrict__ BpR,
    const float* __restrict__ meanW, const float* __restrict__ lsW,
    float* __restrict__ headWpk)
{
    int bid = blockIdx.x;
    if (bid < 1120) {
        PK_body(bid * 256 + threadIdx.x, mpW1, mpW2, phW1, phW2, rhoW, Bp1e, Bp2e, BpC1, BpC2, BpR);
    } else {
        // headWpk f32[256][8]: q<4 mean, q>=4 logstd
        int idx = threadIdx.x;
        #pragma unroll
        for (int r = 0; r < 8; ++r) {
            int f = r * 256 + idx;
            int k = f >> 3, q = f & 7;
            headWpk[f] = (q < 4) ? meanW[k * 4 + q] : lsW[k * 4 + (q - 4)];
        }
    }
}

// ================= GA: fused edge-input build + edge MLP + softmax-aggregate + node-input build =================
// 80 rows/block = 4 batches; 512 threads = 8 waves. Operand-swapped MFMAs, hi-only L2 weights.
// m-loop unrolled by 2 (4 h-buffers, R10-proven). Edge inputs built in LDS (EinL) by 80 prologue threads.
__global__ __launch_bounds__(512) void GA(
    const u16* __restrict__ Bp1, const u16* __restrict__ Bp2,
    const float* __restrict__ b1, const float* __restrict__ b2,
    const float* __restrict__ eaW, const float* __restrict__ eab,
    const int* __restrict__ inc, const float* __restrict__ obs,
    const float* __restrict__ agv, const float* __restrict__ gv,
    const int* __restrict__ src, const int* __restrict__ dst, const int* __restrict__ pred,
    u16* __restrict__ Nin)
{
    __shared__ u16 hb[4][16 * 256];     // 32768 B, 4 h-tile buffers, swizzled
    __shared__ u16 mpb[80 * 128];       // 20480 B, mp values, swizzled
    __shared__ u16 EinL[80 * 40];       // 6400 B, edge inputs [x_hi(8)|x_lo(8)] @ stride 40 u16
    __shared__ float spart[8][80];      // per-wave e-score partials
    __shared__ float wbuf[80];
    __shared__ int rowb[80];
    __shared__ int incL[20];
    // total ~63 KB -> 2 blocks/CU

    const int tid = threadIdx.x;
    const int w = tid >> 6, lane = tid & 63;
    const int l15 = lane & 15, gq = lane >> 4;
    char* hbc = (char*)hb;
    char* mpc = (char*)mpb;

    if (tid < 20) incL[tid] = inc[tid];

    // ---- inline P1: build 80 edge-input rows into EinL ----
    if (tid < 80) {
        int bl = tid / 20, p = tid - bl * 20;
        int bg = blockIdx.x * 4 + bl;
        int i0 = pred[2 * p], i1 = pred[2 * p + 1];
        const float* gb = gv + (size_t)bg * 40;
        const float* ab = agv + (size_t)bg * 40;
        float inp[8];
        inp[0] = gb[i0] - ab[i0];
        inp[1] = gb[i1] - ab[i1];
        int so = src[p], dd = dst[p];
        const float* ob = obs + (size_t)bg * 85 + 10;
        inp[2] = ob[so * 15 + 0]; inp[3] = ob[so * 15 + 1]; inp[4] = ob[so * 15 + 2];
        inp[5] = ob[dd * 15 + 0]; inp[6] = ob[dd * 15 + 1]; inp[7] = ob[dd * 15 + 2];
        u32 wh[4], wl[4];
        #pragma unroll
        for (int k = 0; k < 4; ++k) {
            u16 h0 = bf16_rne(inp[2 * k]), h1 = bf16_rne(inp[2 * k + 1]);
            u16 l0 = bf16_lo(inp[2 * k], h0), l1 = bf16_lo(inp[2 * k + 1], h1);
            wh[k] = (u32)h0 | ((u32)h1 << 16);
            wl[k] = (u32)l0 | ((u32)l1 << 16);
        }
        *(uint4*)(EinL + tid * 40) = make_uint4(wh[0], wh[1], wh[2], wh[3]);
        *(uint4*)(EinL + tid * 40 + 8) = make_uint4(wl[0], wl[1], wl[2], wl[3]);
    }

    // stage-1 W-frags (tiles 2w, 2w+1; exact 4-group hi/lo) + per-col biases
    bf16x8 B1[2];
    float4 b1v[2];
    #pragma unroll
    for (int t = 0; t < 2; ++t) {
        B1[t] = *(const bf16x8*)(Bp1 + (size_t)(2 * w + t) * 512 + lane * 8);
        b1v[t] = *(const float4*)(b1 + 16 * (2 * w + t) + 4 * gq);
    }
    // stage-2 W-frags (tile n=w), hi only
    bf16x8 B2[8];
    #pragma unroll
    for (int c = 0; c < 8; ++c)
        B2[c] = *(const bf16x8*)(Bp2 + (size_t)((c * 8 + w) * 2) * 512 + lane * 8);
    const float4 b2v = *(const float4*)(b2 + 16 * w + 4 * gq);
    const float4 eav = *(const float4*)(eaW + 16 * w + 4 * gq);

    __syncthreads();   // EinL ready

    auto ldX = [&](int m) {
        return *(const bf16x8*)(EinL + (m * 16 + l15) * 40 + 8 * (gq & 1));
    };
    // ---- stage1: h[row=l15][col=16t+4gq+j] into hb[buf], b64 store ----
    auto stage1 = [&](int buf, const bf16x8& X) {
        #pragma unroll
        for (int t = 0; t < 2; ++t) {
            f32x4 acc = {b1v[t].x, b1v[t].y, b1v[t].z, b1v[t].w};
            acc = MFMA16(B1[t], X, acc);   // swapped: C[m=col][n=row]
            u32 p0 = cvt_pk(fmaxf(acc[0], 0.f), fmaxf(acc[1], 0.f));
            u32 p1 = cvt_pk(fmaxf(acc[2], 0.f), fmaxf(acc[3], 0.f));
            int colu = 16 * (2 * w + t) + 4 * gq;
            int byte = buf * 8192 + ((l15 * 512 + colu * 2) ^ ((l15 & 7) << 4));
            *(uint2*)(hbc + byte) = make_uint2(p0, p1);
        }
    };
    // ---- stage2(m): two indep acc chains; mp write + fused e-dot ----
    auto stage2 = [&](int m, int buf) {
        f32x4 accA = {b2v.x, b2v.y, b2v.z, b2v.w};
        f32x4 accB = {0.f, 0.f, 0.f, 0.f};
        #pragma unroll
        for (int c = 0; c < 4; ++c) {
            int byteA = buf * 8192 + ((l15 * 512 + (2 * c) * 64 + gq * 16) ^ ((l15 & 7) << 4));
            int byteB = buf * 8192 + ((l15 * 512 + (2 * c + 1) * 64 + gq * 16) ^ ((l15 & 7) << 4));
            const bf16x8 HA = *(const bf16x8*)(hbc + byteA);
            const bf16x8 HB = *(const bf16x8*)(hbc + byteB);
            accA = MFMA16(B2[2 * c], HA, accA);
            accB = MFMA16(B2[2 * c + 1], HB, accB);
        }
        float v0 = fmaxf(accA[0] + accB[0], 0.f), v1 = fmaxf(accA[1] + accB[1], 0.f);
        float v2 = fmaxf(accA[2] + accB[2], 0.f), v3 = fmaxf(accA[3] + accB[3], 0.f);
        float ep = v0 * eav.x + v1 * eav.y + v2 * eav.z + v3 * eav.w;
        ep += __shfl_xor(ep, 16, 64);
        ep += __shfl_xor(ep, 32, 64);
        if (gq == 0) spart[w][m * 16 + l15] = ep;
        u32 p0 = cvt_pk(v0, v1), p1 = cvt_pk(v2, v3);
        int r = m * 16 + l15;
        int byte2 = (r * 256 + (16 * w + 4 * gq) * 2) ^ ((r & 15) << 4);
        *(uint2*)(mpc + byte2) = make_uint2(p0, p1);
    };

    // prologue: fill buffers 0,1
    {
        bf16x8 X0 = ldX(0);
        bf16x8 X1 = ldX(1);
        stage1(0, X0);
        stage1(1, X1);
    }
    __syncthreads();
    // interval 0: compute m=0,1; fill m=2,3
    {
        bf16x8 X2 = ldX(2);
        bf16x8 X3 = ldX(3);
        stage2(0, 0);
        stage2(1, 1);
        stage1(2, X2);
        stage1(3, X3);
    }
    __syncthreads();
    // interval 1: compute m=2,3; fill buf0 <- m=4
    {
        bf16x8 X4 = ldX(4);
        stage2(2, 2);
        stage2(3, 3);
        stage1(0, X4);
    }
    __syncthreads();
    // interval 2: compute m=4
    stage2(4, 0);
    __syncthreads();

    // ---- softmax weights for 20 (batch,obj) pairs ∥ Nin cols 0..31 build on idle tail ----
    if (tid < 20) {
        int bl = tid / 5, o = tid - bl * 5;
        const float e0 = eab[0];
        int rr[4]; float ee[4];
        #pragma unroll
        for (int i = 0; i < 4; ++i) {
            rr[i] = bl * 20 + incL[o * 4 + i];
            float e = e0;
            #pragma unroll
            for (int ww = 0; ww < 8; ++ww) e += spart[ww][rr[i]];
            ee[i] = e;
        }
        float mx = fmaxf(fmaxf(ee[0], ee[1]), fmaxf(ee[2], ee[3]));
        float ex[4]; float den = 0.f;
        #pragma unroll
        for (int i = 0; i < 4; ++i) { ex[i] = __expf(ee[i] - mx); den += ex[i]; }
        float inv = 1.0f / den;
        #pragma unroll
        for (int i = 0; i < 4; ++i) {
            wbuf[tid * 4 + i] = ex[i] * inv;
            rowb[tid * 4 + i] = rr[i];
        }
    } else if (tid >= 320 && tid < 480) {
        // P2 work: 160 threads = 20 node rows x 8 quad-col groups
        int t2 = tid - 320;
        int p = t2 >> 3, q = t2 & 7;
        int bl = p / 5, o = p - bl * 5;
        const float* body = obs + (size_t)(blockIdx.x * 4 + bl) * 85;
        const float* op = body + 10 + o * 15;
        float v[4];
        #pragma unroll
        for (int jj = 0; jj < 4; ++jj) {
            int col = 4 * q + jj;
            v[jj] = (col < 10) ? body[col] : (col < 25) ? op[col - 10] : 0.0f;
        }
        int grow = blockIdx.x * 20 + p;
        *(uint2*)(Nin + (size_t)grow * 160 + 4 * q) =
            make_uint2(cvt_pk(v[0], v[1]), cvt_pk(v[2], v[3]));
    }
    __syncthreads();

    // ---- weighted gather -> Nin cols 32..159 ----
    if (tid < 320) {
        int p = tid >> 4, cb = tid & 15;
        float acc[8] = {0, 0, 0, 0, 0, 0, 0, 0};
        #pragma unroll
        for (int i = 0; i < 4; ++i) {
            int r = rowb[p * 4 + i];
            float wi = wbuf[p * 4 + i];
            int byte = (r * 256 + cb * 16) ^ ((r & 15) << 4);
            uint4 v = *(const uint4*)(mpc + byte);
            acc[0] = fmaf(wi, blo(v.x), acc[0]);
            acc[1] = fmaf(wi, bhi(v.x), acc[1]);
            acc[2] = fmaf(wi, blo(v.y), acc[2]);
            acc[3] = fmaf(wi, bhi(v.y), acc[3]);
            acc[4] = fmaf(wi, blo(v.z), acc[4]);
            acc[5] = fmaf(wi, bhi(v.z), acc[5]);
            acc[6] = fmaf(wi, blo(v.w), acc[6]);
            acc[7] = fmaf(wi, bhi(v.w), acc[7]);
        }
        uint4 ov;
        ov.x = cvt_pk(acc[0], acc[1]);
        ov.y = cvt_pk(acc[2], acc[3]);
        ov.z = cvt_pk(acc[4], acc[5]);
        ov.w = cvt_pk(acc[6], acc[7]);
        int grow = blockIdx.x * 20 + p;
        *(uint4*)(Nin + (size_t)grow * 160 + 32 + cb * 8) = ov;
    }
}

// ================= GB: fused node MLP + attn-pool + rho + heads -> out =================
// 80 rows/block = 16 batches; 512 threads = 8 waves.
// m-loop unrolled by 2 (4 h-buffers, R10-proven): main-loop barriers 6 -> 4.  (byte-identical to R10)
__global__ __launch_bounds__(512) void GB(
    const u16* __restrict__ Nin, const u16* __restrict__ BpC1, const u16* __restrict__ BpC2,
    const u16* __restrict__ BpR,
    const float* __restrict__ b1, const float* __restrict__ b2,
    const float* __restrict__ saW, const float* __restrict__ sab,
    const float* __restrict__ rhob, const float* __restrict__ headWpk,
    const float* __restrict__ meanb, const float* __restrict__ lsb,
    float* __restrict__ outp)
{
    __shared__ u16 hb[4][16 * 256];      // 32768 B, 4 h-tile buffers; poolw aliases after main loop
    __shared__ u16 phibuf[80 * 132];     // 21120 B bf16 phi (stride 132); aliased as rbuf f32 stride 260
    __shared__ float spart[8][80];       // 2560 B; reused as hpart[512]
    __shared__ float awb[80];            // 320 B

    const int tid = threadIdx.x;
    const int w = tid >> 6, lane = tid & 63;
    const int l15 = lane & 15, gq = lane >> 4;
    const int rowbase = blockIdx.x * 80;
    char* hbc = (char*)hb;
    float* rbuf = (float*)phibuf;        // alias, stride 260 f32 (16640 B <= 21120)
    float* hpart = (float*)spart;
    u32* poolw = (u32*)hb;               // alias over dead hb: 16x132 u32 = 8448 B <= 32768

    // stage-1 W-frags: 5 chunks x 2 tiles, hi only + per-col bias (RESIDENT)
    bf16x8 BC[5][2];
    float4 b1v[2];
    #pragma unroll
    for (int t = 0; t < 2; ++t) b1v[t] = *(const float4*)(b1 + 16 * (2 * w + t) + 4 * gq);
    #pragma unroll
    for (int c = 0; c < 5; ++c)
        #pragma unroll
        for (int t = 0; t < 2; ++t)
            BC[c][t] = *(const bf16x8*)(BpC1 + (size_t)((c * 2) * 16 + 2 * w + t) * 512 + lane * 8);
    // stage-2 W-frags, hi only (RESIDENT)
    bf16x8 B2[8];
    #pragma unroll
    for (int c = 0; c < 8; ++c)
        B2[c] = *(const bf16x8*)(BpC2 + (size_t)((c * 8 + w) * 2) * 512 + lane * 8);
    const float4 b2v = *(const float4*)(b2 + 16 * w + 4 * gq);
    const float4 sav = *(const float4*)(saW + 16 * w + 4 * gq);

    auto loadX = [&](int m, bf16x8* X) {
        #pragma unroll
        for (int c = 0; c < 5; ++c)
            X[c] = *(const bf16x8*)(Nin + (size_t)(rowbase + m * 16 + l15) * 160 + 32 * c + 8 * gq);
    };
    auto stage1 = [&](int buf, const bf16x8* X) {
        f32x4 a0 = {b1v[0].x, b1v[0].y, b1v[0].z, b1v[0].w};
        f32x4 a1 = {b1v[1].x, b1v[1].y, b1v[1].z, b1v[1].w};
        #pragma unroll
        for (int c = 0; c < 5; ++c) {
            a0 = MFMA16(BC[c][0], X[c], a0);
            a1 = MFMA16(BC[c][1], X[c], a1);
        }
        #pragma unroll
        for (int t = 0; t < 2; ++t) {
            const f32x4& a = t ? a1 : a0;
            u32 p0 = cvt_pk(fmaxf(a[0], 0.f), fmaxf(a[1], 0.f));
            u32 p1 = cvt_pk(fmaxf(a[2], 0.f), fmaxf(a[3], 0.f));
            int colu = 16 * (2 * w + t) + 4 * gq;
            int byte = buf * 8192 + ((l15 * 512 + colu * 2) ^ ((l15 & 7) << 4));
            *(uint2*)(hbc + byte) = make_uint2(p0, p1);
        }
    };
    auto stage2 = [&](int m, int buf) {
        f32x4 accA = {b2v.x, b2v.y, b2v.z, b2v.w};
        f32x4 accB = {0.f, 0.f, 0.f, 0.f};
        #pragma unroll
        for (int c = 0; c < 4; ++c) {
            int byteA = buf * 8192 + ((l15 * 512 + (2 * c) * 64 + gq * 16) ^ ((l15 & 7) << 4));
            int byteB = buf * 8192 + ((l15 * 512 + (2 * c + 1) * 64 + gq * 16) ^ ((l15 & 7) << 4));
            const bf16x8 HA = *(const bf16x8*)(hbc + byteA);
            const bf16x8 HB = *(const bf16x8*)(hbc + byteB);
            accA = MFMA16(B2[2 * c], HA, accA);
            accB = MFMA16(B2[2 * c + 1], HB, accB);
        }
        float v0 = fmaxf(accA[0] + accB[0], 0.f), v1 = fmaxf(accA[1] + accB[1], 0.f);
        float v2 = fmaxf(accA[2] + accB[2], 0.f), v3 = fmaxf(accA[3] + accB[3], 0.f);
        int r = m * 16 + l15;
        *(uint2*)((char*)phibuf + r * 264 + (16 * w + 4 * gq) * 2) =
            make_uint2(cvt_pk(v0, v1), cvt_pk(v2, v3));
        float sp = v0 * sav.x + v1 * sav.y + v2 * sav.z + v3 * sav.w;
        sp += __shfl_xor(sp, 16, 64);
        sp += __shfl_xor(sp, 32, 64);
        if (gq == 0) spart[w][r] = sp;
    };

    // prologue: fill buffers 0,1
    {
        bf16x8 X0[5], X1[5];
        loadX(0, X0);
        loadX(1, X1);
        stage1(0, X0);
        stage1(1, X1);
    }
    __syncthreads();
    // interval 0: compute m=0,1; prefetch+stage1 m=2,3
    {
        bf16x8 X2[5], X3[5];
        loadX(2, X2);
        loadX(3, X3);
        stage2(0, 0);
        stage2(1, 1);
        stage1(2, X2);
        stage1(3, X3);
    }
    __syncthreads();
    // interval 1: compute m=2,3; prefetch+stage1 m=4 (reuse buf 0)
    {
        bf16x8 X4[5];
        loadX(4, X4);
        stage2(2, 2);
        stage2(3, 3);
        stage1(0, X4);
    }
    __syncthreads();
    // interval 2: compute m=4
    stage2(4, 0);
    __syncthreads();

    // ---- softmax over 5 objects per batch ----
    if (tid < 16) {
        const float s0c = sab[0];
        float ss[5];
        #pragma unroll
        for (int o = 0; o < 5; ++o) {
            float s = s0c;
            #pragma unroll
            for (int ww = 0; ww < 8; ++ww) s += spart[ww][tid * 5 + o];
            ss[o] = s;
        }
        float mx = fmaxf(fmaxf(fmaxf(ss[0], ss[1]), fmaxf(ss[2], ss[3])), ss[4]);
        float ex[5]; float den = 0.f;
        #pragma unroll
        for (int o = 0; o < 5; ++o) { ex[o] = __expf(ss[o] - mx); den += ex[o]; }
        float inv = 1.0f / den;
        #pragma unroll
        for (int o = 0; o < 5; ++o) awb[tid * 5 + o] = ex[o] * inv;
    }
    __syncthreads();

    // ---- pooling: 1024 u32 words (2 cols each) -> poolw (aliases dead hb) packed bf16 hi|lo ----
    #pragma unroll
    for (int rep = 0; rep < 2; ++rep) {
        int idx = rep * 512 + tid;       // < 1024
        int b = idx >> 6, cw = idx & 63; // u32 word = cols 2cw, 2cw+1
        float p0 = 0.f, p1 = 0.f;
        #pragma unroll
        for (int o = 0; o < 5; ++o) {
            u32 v = *(const u32*)((const char*)phibuf + (size_t)(b * 5 + o) * 264 + cw * 4);
            float a = awb[b * 5 + o];
            p0 = fmaf(a, blo(v), p0);
            p1 = fmaf(a, bhi(v), p1);
        }
        u16 h0 = bf16_rne(p0); u16 l0 = bf16_lo(p0, h0);
        u16 h1 = bf16_rne(p1); u16 l1 = bf16_lo(p1, h1);
        *(uint2*)(poolw + b * 132 + 2 * cw) =
            make_uint2((u32)h0 | ((u32)l0 << 16), (u32)h1 | ((u32)l1 << 16));
    }
    __syncthreads();   // phibuf dead after this point; rbuf may overwrite

    // ---- rho (swapped): A = pooled hi+lo, B = rhoW hi only ----
    {
        float4 rb0 = *(const float4*)(rhob + 16 * (2 * w + 0) + 4 * gq);
        float4 rb1 = *(const float4*)(rhob + 16 * (2 * w + 1) + 4 * gq);
        f32x4 acc0 = {rb0.x, rb0.y, rb0.z, rb0.w};
        f32x4 acc1 = {rb1.x, rb1.y, rb1.z, rb1.w};
        #pragma unroll
        for (int c = 0; c < 4; ++c) {
            uint4 q0 = *(const uint4*)(poolw + l15 * 132 + 32 * c + 8 * gq);
            uint4 q1 = *(const uint4*)(poolw + l15 * 132 + 32 * c + 8 * gq + 4);
            u32 ws[8] = {q0.x, q0.y, q0.z, q0.w, q1.x, q1.y, q1.z, q1.w};
            bf16x8 Ph, Pl;
            #pragma unroll
            for (int i = 0; i < 8; ++i) {
                Ph[i] = (short)(ws[i] & 0xffffu);
                Pl[i] = (short)(ws[i] >> 16);
            }
            #pragma unroll
            for (int t = 0; t < 2; ++t) {
                bf16x8 Bh = *(const bf16x8*)(BpR + (size_t)((c * 16 + 2 * w + t) * 2 + 0) * 512 + lane * 8);
                f32x4& a = t ? acc1 : acc0;
                a = MFMA16(Bh, Ph, a);
                a = MFMA16(Bh, Pl, a);
            }
        }
        #pragma unroll
        for (int t = 0; t < 2; ++t) {
            const f32x4& a = t ? acc1 : acc0;
            float4 v;
            v.x = fmaxf(a[0], 0.f); v.y = fmaxf(a[1], 0.f);
            v.z = fmaxf(a[2], 0.f); v.w = fmaxf(a[3], 0.f);
            *(float4*)(rbuf + l15 * 260 + 16 * (2 * w + t) + 4 * gq) = v;
        }
    }
    __syncthreads();

    // ---- heads split-k: 512 threads = 4 k-splits x (16 b x 8 q) ----
    {
        int s = tid >> 7, p = tid & 127;
        int b = p >> 3, q = p & 7;
        const float* rrow = rbuf + b * 260 + s * 64;
        const float* wcol = headWpk + s * 64 * 8 + q;
        float acc = 0.f;
        #pragma unroll 8
        for (int k = 0; k < 64; ++k)
            acc = fmaf(rrow[k], wcol[k * 8], acc);
        hpart[s * 128 + p] = acc;
    }
    __syncthreads();
    if (tid < 128) {
        int b = tid >> 3, q = tid & 7;
        float a = hpart[tid] + hpart[128 + tid] + hpart[256 + tid] + hpart[384 + tid];
        int bg = blockIdx.x * 16 + b;
        if (q < 4) {
            outp[(size_t)bg * 4 + q] = a + meanb[q];
        } else {
            float l = a + lsb[q - 4];
            outp[65536 + (size_t)bg * 4 + (q - 4)] = fminf(fmaxf(l, -20.0f), 2.0f);
        }
    }
}

extern "C" void kernel_launch(void* const* d_in, const int* in_sizes, int n_in,
                              void* d_out, int out_size, void* d_ws, size_t ws_size,
                              hipStream_t stream)
{
    const float* obs   = (const float*)d_in[0];
    const float* ag    = (const float*)d_in[1];
    const float* g     = (const float*)d_in[2];
    const float* mpW1  = (const float*)d_in[3];
    const float* mpb1  = (const float*)d_in[4];
    const float* mpW2  = (const float*)d_in[5];
    const float* mpb2  = (const float*)d_in[6];
    const float* eaW   = (const float*)d_in[7];
    const float* eab   = (const float*)d_in[8];
    const float* phW1  = (const float*)d_in[9];
    const float* phb1  = (const float*)d_in[10];
    const float* phW2  = (const float*)d_in[11];
    const float* phb2  = (const float*)d_in[12];
    const float* saW   = (const float*)d_in[13];
    const float* sab   = (const float*)d_in[14];
    const float* rhoW  = (const float*)d_in[15];
    const float* rhob  = (const float*)d_in[16];
    const float* meanW = (const float*)d_in[17];
    const float* meanb = (const float*)d_in[18];
    const float* lsW   = (const float*)d_in[19];
    const float* lsb   = (const float*)d_in[20];
    const int*   src   = (const int*)d_in[21];
    const int*   dst   = (const int*)d_in[22];
    const int*   inc   = (const int*)d_in[23];
    const int*   pred  = (const int*)d_in[24];

    // workspace layout (bytes):
    //  Nin  (u16 81920x160) : [10485760, 36700160)
    //  Bp1e (u16 8192)      : [36700160, +16384)
    //  Bp2e (u16 65536)     : [36716544, +131072)
    //  BpC1 (u16 81920)     : [36847616, +163840)
    //  BpC2 (u16 65536)     : [37011456, +131072)
    //  BpR  (u16 65536)     : [37142528, +131072)
    //  headWpk (f32 2048)   : [37273600, +8192)
    char* ws = (char*)d_ws;
    u16* Nin  = (u16*)(ws + 10485760ull);
    u16* Bp1e = (u16*)(ws + 36700160ull);
    u16* Bp2e = (u16*)(ws + 36716544ull);
    u16* BpC1 = (u16*)(ws + 36847616ull);
    u16* BpC2 = (u16*)(ws + 37011456ull);
    u16* BpR  = (u16*)(ws + 37142528ull);
    float* headWpk = (float*)(ws + 37273600ull);

    hipLaunchKernelGGL(PREP, dim3(1121), dim3(256), 0, stream,
                       mpW1, mpW2, phW1, phW2, rhoW, Bp1e, Bp2e, BpC1, BpC2, BpR,
                       meanW, lsW, headWpk);
    hipLaunchKernelGGL(GA, dim3(4096), dim3(512), 0, stream,
                       Bp1e, Bp2e, mpb1, mpb2, eaW, eab, inc, obs,
                       ag, g, src, dst, pred, Nin);
    hipLaunchKernelGGL(GB, dim3(1024), dim3(512), 0, stream,
                       Nin, BpC1, BpC2, BpR, phb1, phb2, saW, sab, rhob,
                       headWpk, meanb, lsb, (float*)d_out);
}

// Round 14
// 97.523 us; speedup vs baseline: 1.0792x; 1.0429x over previous
//
#include <hip/hip_runtime.h>
#include <cstdint>
#include <cstddef>

typedef unsigned short u16;
typedef unsigned int u32;
typedef __attribute__((ext_vector_type(8))) short bf16x8;
typedef __attribute__((ext_vector_type(4))) float f32x4;

#define MFMA16(A, B, C) __builtin_amdgcn_mfma_f32_16x16x32_bf16((A), (B), (C), 0, 0, 0)

__device__ __forceinline__ u16 bf16_rne(float x) {
    u32 u = __float_as_uint(x);
    u += 0x7fffu + ((u >> 16) & 1u);
    return (u16)(u >> 16);
}
__device__ __forceinline__ float bf2f(u16 h) { return __uint_as_float((u32)h << 16); }
__device__ __forceinline__ u16 bf16_lo(float x, u16 hi) { return bf16_rne(x - bf2f(hi)); }
__device__ __forceinline__ float blo(u32 u) { return __uint_as_float(u << 16); }
__device__ __forceinline__ float bhi(u32 u) { return __uint_as_float(u & 0xffff0000u); }
// packed f32x2 -> bf16x2 (lo<-a, hi<-b), RNE
__device__ __forceinline__ u32 cvt_pk(float a, float b) {
    u32 r;
    asm("v_cvt_pk_bf16_f32 %0, %1, %2" : "=v"(r) : "v"(a), "v"(b));
    return r;
}

// ================= prep bodies =================
// B-frag (16x16x32): lane l, elem i holds B[k = 8*(l>>4)+i][col = 16*tile + (l&15)]
// (same bytes as A-frag give A[row=l&15][k=8*(l>>4)+i] -> operand-swap transposes C)
__device__ __forceinline__ void PK_body(int tid,
    const float* __restrict__ mpW1, const float* __restrict__ mpW2,
    const float* __restrict__ phW1, const float* __restrict__ phW2,
    const float* __restrict__ rhoW,
    u16* __restrict__ Bp1e, u16* __restrict__ Bp2e,
    u16* __restrict__ BpC1, u16* __restrict__ BpC2, u16* __restrict__ BpR)
{
    if (tid < 8192) {
        // edge L1: 16 tiles x 512, 4-group trick [w_hi, w_hi, w_lo, w_lo]
        int t = tid >> 9, r = tid & 511;
        int l = r >> 3, i = r & 7, g = l >> 4, l15 = l & 15;
        float w = mpW1[i * 256 + 16 * t + l15];
        u16 h = bf16_rne(w);
        Bp1e[tid] = (g < 2) ? h : bf16_lo(w, h);
    } else if (tid < 73728) {
        // edge L2: [(c*8+n)*2+s][512] from mpW2 (256x128)
        int f = tid - 8192;
        int b5 = f >> 9, r = f & 511;
        int l = r >> 3, i = r & 7, g = l >> 4, l15 = l & 15;
        int s = b5 & 1, cn = b5 >> 1, c = cn >> 3, n = cn & 7;
        int kk = 32 * c + 8 * g + i;
        float w = mpW2[kk * 128 + 16 * n + l15];
        u16 h = bf16_rne(w);
        Bp2e[f] = s ? bf16_lo(w, h) : h;
    } else if (tid < 155648) {
        // node L1: [(c*2+s)*16+t][512] from phW1 (153x256), K perm: 0..24 direct, 25..31 zero, 32..159 -> 25..152
        int f = tid - 73728;
        int b5 = f >> 9, r = f & 511;
        int l = r >> 3, i = r & 7, g = l >> 4, l15 = l & 15;
        int t = b5 & 15, cs = b5 >> 4, s = cs & 1, c = cs >> 1;
        int kk = 32 * c + 8 * g + i;
        int kp = kk < 25 ? kk : (kk < 32 ? -1 : kk - 7);
        float w = (kp < 0) ? 0.0f : phW1[kp * 256 + 16 * t + l15];
        u16 h = bf16_rne(w);
        BpC1[f] = s ? bf16_lo(w, h) : h;
    } else if (tid < 221184) {
        // node L2: from phW2 (256x128)
        int f = tid - 155648;
        int b5 = f >> 9, r = f & 511;
        int l = r >> 3, i = r & 7, g = l >> 4, l15 = l & 15;
        int s = b5 & 1, cn = b5 >> 1, c = cn >> 3, n = cn & 7;
        int kk = 32 * c + 8 * g + i;
        float w = phW2[kk * 128 + 16 * n + l15];
        u16 h = bf16_rne(w);
        BpC2[f] = s ? bf16_lo(w, h) : h;
    } else {
        // rho: [(c*16+t)*2+s][512] from rhoW (128x256)
        int f = tid - 221184;
        int b5 = f >> 9, r = f & 511;
        int l = r >> 3, i = r & 7, g = l >> 4, l15 = l & 15;
        int s = b5 & 1, ct = b5 >> 1, c = ct >> 4, t = ct & 15;
        int kk = 32 * c + 8 * g + i;
        float w = rhoW[kk * 256 + 16 * t + l15];
        u16 h = bf16_rne(w);
        BpR[f] = s ? bf16_lo(w, h) : h;
    }
}

// Ein[row][16] bf16 : [x_hi(8) | x_lo(8)]  (GA reconstructs the 4-group via gq&1)
__device__ __forceinline__ void P1_body(int row,
    const float* __restrict__ obs, const float* __restrict__ ag, const float* __restrict__ g,
    const int* __restrict__ src, const int* __restrict__ dst, const int* __restrict__ pred,
    u16* __restrict__ Ein)
{
    int b = row / 20, p = row - b * 20;
    float inp[8];
    int i0 = pred[2 * p], i1 = pred[2 * p + 1];
    const float* gb = g + (size_t)b * 40;
    const float* ab = ag + (size_t)b * 40;
    inp[0] = gb[i0] - ab[i0];
    inp[1] = gb[i1] - ab[i1];
    int so = src[p], dd = dst[p];
    const float* ob = obs + (size_t)b * 85 + 10;
    inp[2] = ob[so * 15 + 0]; inp[3] = ob[so * 15 + 1]; inp[4] = ob[so * 15 + 2];
    inp[5] = ob[dd * 15 + 0]; inp[6] = ob[dd * 15 + 1]; inp[7] = ob[dd * 15 + 2];

    u32 wh[4], wl[4];
    #pragma unroll
    for (int k = 0; k < 4; ++k) {
        u16 h0 = bf16_rne(inp[2 * k]), h1 = bf16_rne(inp[2 * k + 1]);
        u16 l0 = bf16_lo(inp[2 * k], h0), l1 = bf16_lo(inp[2 * k + 1], h1);
        wh[k] = (u32)h0 | ((u32)h1 << 16);
        wl[k] = (u32)l0 | ((u32)l1 << 16);
    }
    uint4* d4 = (uint4*)(Ein + (size_t)row * 16);
    d4[0] = make_uint4(wh[0], wh[1], wh[2], wh[3]);
    d4[1] = make_uint4(wl[0], wl[1], wl[2], wl[3]);
}

// ================= PREP: PK + P1 + headWpk fused =================
__global__ __launch_bounds__(256) void PREP(
    const float* __restrict__ mpW1, const float* __restrict__ mpW2,
    const float* __restrict__ phW1, const float* __restrict__ phW2,
    const float* __restrict__ rhoW,
    u16* __restrict__ Bp1e, u16* __restrict__ Bp2e,
    u16* __restrict__ BpC1, u16* __restrict__ BpC2, u16* __restrict__ BpR,
    const float* __restrict__ obs, const float* __restrict__ ag, const float* __restrict__ g,
    const int* __restrict__ src, const int* __restrict__ dst, const int* __restrict__ pred,
    u16* __restrict__ Ein,
    const float* __restrict__ meanW, const float* __restrict__ lsW,
    float* __restrict__ headWpk)
{
    int bid = blockIdx.x;
    if (bid < 1120) {
        PK_body(bid * 256 + threadIdx.x, mpW1, mpW2, phW1, phW2, rhoW, Bp1e, Bp2e, BpC1, BpC2, BpR);
    } else if (bid < 2400) {
        P1_body((bid - 1120) * 256 + threadIdx.x, obs, ag, g, src, dst, pred, Ein);
    } else {
        // headWpk f32[256][8]: q<4 mean, q>=4 logstd
        int idx = threadIdx.x;
        #pragma unroll
        for (int r = 0; r < 8; ++r) {
            int f = r * 256 + idx;
            int k = f >> 3, q = f & 7;
            headWpk[f] = (q < 4) ? meanW[k * 4 + q] : lsW[k * 4 + (q - 4)];
        }
    }
}

// ================= GA: fused edge MLP + softmax-aggregate + node-input build =================
// 80 rows/block = 4 batches; 512 threads = 8 waves. Operand-swapped MFMAs, hi-only L2 weights.
// m-loop unrolled by 2 (4 h-buffers): 2 tiles per barrier interval -> half the barrier stalls.
__global__ __launch_bounds__(512) void GA(
    const u16* __restrict__ Ein, const u16* __restrict__ Bp1, const u16* __restrict__ Bp2,
    const float* __restrict__ b1, const float* __restrict__ b2,
    const float* __restrict__ eaW, const float* __restrict__ eab,
    const int* __restrict__ inc, const float* __restrict__ obs,
    u16* __restrict__ Nin)
{
    __shared__ u16 hb[4][16 * 256];     // 32 KB, 4 h-tile buffers, swizzled
    __shared__ u16 mpb[80 * 128];       // 20 KB, mp values, swizzled
    __shared__ float spart[8][80];      // per-wave e-score partials
    __shared__ float wbuf[80];
    __shared__ int rowb[80];
    __shared__ int incL[20];

    const int tid = threadIdx.x;
    const int w = tid >> 6, lane = tid & 63;
    const int l15 = lane & 15, gq = lane >> 4;
    const int rowbase = blockIdx.x * 80;
    char* hbc = (char*)hb;
    char* mpc = (char*)mpb;

    if (tid < 20) incL[tid] = inc[tid];

    // stage-1 W-frags (tiles 2w, 2w+1; exact 4-group hi/lo) + per-col biases
    bf16x8 B1[2];
    float4 b1v[2];
    #pragma unroll
    for (int t = 0; t < 2; ++t) {
        B1[t] = *(const bf16x8*)(Bp1 + (size_t)(2 * w + t) * 512 + lane * 8);
        b1v[t] = *(const float4*)(b1 + 16 * (2 * w + t) + 4 * gq);
    }
    // stage-2 W-frags (tile n=w), hi only
    bf16x8 B2[8];
    #pragma unroll
    for (int c = 0; c < 8; ++c)
        B2[c] = *(const bf16x8*)(Bp2 + (size_t)((c * 8 + w) * 2) * 512 + lane * 8);
    const float4 b2v = *(const float4*)(b2 + 16 * w + 4 * gq);
    const float4 eav = *(const float4*)(eaW + 16 * w + 4 * gq);

    auto ldX = [&](int m) {
        return *(const bf16x8*)(Ein + (size_t)(rowbase + m * 16 + l15) * 16 + 8 * (gq & 1));
    };
    // ---- stage1: h[row=l15][col=16t+4gq+j] into hb[buf], b64 store ----
    auto stage1 = [&](int buf, const bf16x8& X) {
        #pragma unroll
        for (int t = 0; t < 2; ++t) {
            f32x4 acc = {b1v[t].x, b1v[t].y, b1v[t].z, b1v[t].w};
            acc = MFMA16(B1[t], X, acc);   // swapped: C[m=col][n=row]
            u32 p0 = cvt_pk(fmaxf(acc[0], 0.f), fmaxf(acc[1], 0.f));
            u32 p1 = cvt_pk(fmaxf(acc[2], 0.f), fmaxf(acc[3], 0.f));
            int colu = 16 * (2 * w + t) + 4 * gq;
            int byte = buf * 8192 + ((l15 * 512 + colu * 2) ^ ((l15 & 7) << 4));
            *(uint2*)(hbc + byte) = make_uint2(p0, p1);
        }
    };
    // ---- stage2(m): two indep acc chains; mp write + fused e-dot ----
    auto stage2 = [&](int m, int buf) {
        f32x4 accA = {b2v.x, b2v.y, b2v.z, b2v.w};
        f32x4 accB = {0.f, 0.f, 0.f, 0.f};
        #pragma unroll
        for (int c = 0; c < 4; ++c) {
            int byteA = buf * 8192 + ((l15 * 512 + (2 * c) * 64 + gq * 16) ^ ((l15 & 7) << 4));
            int byteB = buf * 8192 + ((l15 * 512 + (2 * c + 1) * 64 + gq * 16) ^ ((l15 & 7) << 4));
            const bf16x8 HA = *(const bf16x8*)(hbc + byteA);
            const bf16x8 HB = *(const bf16x8*)(hbc + byteB);
            accA = MFMA16(B2[2 * c], HA, accA);
            accB = MFMA16(B2[2 * c + 1], HB, accB);
        }
        float v0 = fmaxf(accA[0] + accB[0], 0.f), v1 = fmaxf(accA[1] + accB[1], 0.f);
        float v2 = fmaxf(accA[2] + accB[2], 0.f), v3 = fmaxf(accA[3] + accB[3], 0.f);
        float ep = v0 * eav.x + v1 * eav.y + v2 * eav.z + v3 * eav.w;
        ep += __shfl_xor(ep, 16, 64);
        ep += __shfl_xor(ep, 32, 64);
        if (gq == 0) spart[w][m * 16 + l15] = ep;
        u32 p0 = cvt_pk(v0, v1), p1 = cvt_pk(v2, v3);
        int r = m * 16 + l15;
        int byte2 = (r * 256 + (16 * w + 4 * gq) * 2) ^ ((r & 15) << 4);
        *(uint2*)(mpc + byte2) = make_uint2(p0, p1);
    };

    // prologue: fill buffers 0,1
    {
        bf16x8 X0 = ldX(0);
        bf16x8 X1 = ldX(1);
        stage1(0, X0);
        stage1(1, X1);
    }
    __syncthreads();
    // interval 0: compute m=0,1; prefetch+stage1 m=2,3
    {
        bf16x8 X2 = ldX(2);
        bf16x8 X3 = ldX(3);
        stage2(0, 0);
        stage2(1, 1);
        stage1(2, X2);
        stage1(3, X3);
    }
    __syncthreads();
    // interval 1: compute m=2,3; prefetch+stage1 m=4 (reuse buf 0)
    {
        bf16x8 X4 = ldX(4);
        stage2(2, 2);
        stage2(3, 3);
        stage1(0, X4);
    }
    __syncthreads();
    // interval 2: compute m=4
    stage2(4, 0);
    __syncthreads();

    // ---- softmax weights for 20 (batch,obj) pairs ∥ Nin cols 0..31 build on idle tail ----
    if (tid < 20) {
        int bl = tid / 5, o = tid - bl * 5;
        const float e0 = eab[0];
        int rr[4]; float ee[4];
        #pragma unroll
        for (int i = 0; i < 4; ++i) {
            rr[i] = bl * 20 + incL[o * 4 + i];
            float e = e0;
            #pragma unroll
            for (int ww = 0; ww < 8; ++ww) e += spart[ww][rr[i]];
            ee[i] = e;
        }
        float mx = fmaxf(fmaxf(ee[0], ee[1]), fmaxf(ee[2], ee[3]));
        float ex[4]; float den = 0.f;
        #pragma unroll
        for (int i = 0; i < 4; ++i) { ex[i] = __expf(ee[i] - mx); den += ex[i]; }
        float inv = 1.0f / den;
        #pragma unroll
        for (int i = 0; i < 4; ++i) {
            wbuf[tid * 4 + i] = ex[i] * inv;
            rowb[tid * 4 + i] = rr[i];
        }
    } else if (tid >= 320 && tid < 480) {
        // P2 work: 160 threads = 20 node rows x 8 quad-col groups
        int t2 = tid - 320;
        int p = t2 >> 3, q = t2 & 7;
        int bl = p / 5, o = p - bl * 5;
        const float* body = obs + (size_t)(blockIdx.x * 4 + bl) * 85;
        const float* op = body + 10 + o * 15;
        float v[4];
        #pragma unroll
        for (int jj = 0; jj < 4; ++jj) {
            int col = 4 * q + jj;
            v[jj] = (col < 10) ? body[col] : (col < 25) ? op[col - 10] : 0.0f;
        }
        int grow = blockIdx.x * 20 + p;
        *(uint2*)(Nin + (size_t)grow * 160 + 4 * q) =
            make_uint2(cvt_pk(v[0], v[1]), cvt_pk(v[2], v[3]));
    }
    __syncthreads();

    // ---- weighted gather -> Nin cols 32..159 ----
    if (tid < 320) {
        int p = tid >> 4, cb = tid & 15;
        float acc[8] = {0, 0, 0, 0, 0, 0, 0, 0};
        #pragma unroll
        for (int i = 0; i < 4; ++i) {
            int r = rowb[p * 4 + i];
            float wi = wbuf[p * 4 + i];
            int byte = (r * 256 + cb * 16) ^ ((r & 15) << 4);
            uint4 v = *(const uint4*)(mpc + byte);
            acc[0] = fmaf(wi, blo(v.x), acc[0]);
            acc[1] = fmaf(wi, bhi(v.x), acc[1]);
            acc[2] = fmaf(wi, blo(v.y), acc[2]);
            acc[3] = fmaf(wi, bhi(v.y), acc[3]);
            acc[4] = fmaf(wi, blo(v.z), acc[4]);
            acc[5] = fmaf(wi, bhi(v.z), acc[5]);
            acc[6] = fmaf(wi, blo(v.w), acc[6]);
            acc[7] = fmaf(wi, bhi(v.w), acc[7]);
        }
        uint4 ov;
        ov.x = cvt_pk(acc[0], acc[1]);
        ov.y = cvt_pk(acc[2], acc[3]);
        ov.z = cvt_pk(acc[4], acc[5]);
        ov.w = cvt_pk(acc[6], acc[7]);
        int grow = blockIdx.x * 20 + p;
        *(uint4*)(Nin + (size_t)grow * 160 + 32 + cb * 8) = ov;
    }
}

// ================= GB: fused node MLP + attn-pool + rho + heads -> out =================
// 80 rows/block = 16 batches; 512 threads = 8 waves.
// m-loop unrolled by 2 (4 h-buffers, mirrors GA's R9 win): main-loop barriers 6 -> 4.
__global__ __launch_bounds__(512) void GB(
    const u16* __restrict__ Nin, const u16* __restrict__ BpC1, const u16* __restrict__ BpC2,
    const u16* __restrict__ BpR,
    const float* __restrict__ b1, const float* __restrict__ b2,
    const float* __restrict__ saW, const float* __restrict__ sab,
    const float* __restrict__ rhob, const float* __restrict__ headWpk,
    const float* __restrict__ meanb, const float* __restrict__ lsb,
    float* __restrict__ outp)
{
    __shared__ u16 hb[4][16 * 256];      // 32768 B, 4 h-tile buffers; poolw aliases after main loop
    __shared__ u16 phibuf[80 * 132];     // 21120 B bf16 phi (stride 132); aliased as rbuf f32 stride 260
    __shared__ float spart[8][80];       // 2560 B; reused as hpart[512]
    __shared__ float awb[80];            // 320 B
    // total 56768 B -> 2 blocks/CU

    const int tid = threadIdx.x;
    const int w = tid >> 6, lane = tid & 63;
    const int l15 = lane & 15, gq = lane >> 4;
    const int rowbase = blockIdx.x * 80;
    char* hbc = (char*)hb;
    float* rbuf = (float*)phibuf;        // alias, stride 260 f32 (16640 B <= 21120)
    float* hpart = (float*)spart;
    u32* poolw = (u32*)hb;               // alias over dead hb: 16x132 u32 = 8448 B <= 32768

    // stage-1 W-frags: 5 chunks x 2 tiles, hi only + per-col bias (RESIDENT)
    bf16x8 BC[5][2];
    float4 b1v[2];
    #pragma unroll
    for (int t = 0; t < 2; ++t) b1v[t] = *(const float4*)(b1 + 16 * (2 * w + t) + 4 * gq);
    #pragma unroll
    for (int c = 0; c < 5; ++c)
        #pragma unroll
        for (int t = 0; t < 2; ++t)
            BC[c][t] = *(const bf16x8*)(BpC1 + (size_t)((c * 2) * 16 + 2 * w + t) * 512 + lane * 8);
    // stage-2 W-frags, hi only (RESIDENT)
    bf16x8 B2[8];
    #pragma unroll
    for (int c = 0; c < 8; ++c)
        B2[c] = *(const bf16x8*)(BpC2 + (size_t)((c * 8 + w) * 2) * 512 + lane * 8);
    const float4 b2v = *(const float4*)(b2 + 16 * w + 4 * gq);
    const float4 sav = *(const float4*)(saW + 16 * w + 4 * gq);

    auto loadX = [&](int m, bf16x8* X) {
        #pragma unroll
        for (int c = 0; c < 5; ++c)
            X[c] = *(const bf16x8*)(Nin + (size_t)(rowbase + m * 16 + l15) * 160 + 32 * c + 8 * gq);
    };
    auto stage1 = [&](int buf, const bf16x8* X) {
        f32x4 a0 = {b1v[0].x, b1v[0].y, b1v[0].z, b1v[0].w};
        f32x4 a1 = {b1v[1].x, b1v[1].y, b1v[1].z, b1v[1].w};
        #pragma unroll
        for (int c = 0; c < 5; ++c) {
            a0 = MFMA16(BC[c][0], X[c], a0);
            a1 = MFMA16(BC[c][1], X[c], a1);
        }
        #pragma unroll
        for (int t = 0; t < 2; ++t) {
            const f32x4& a = t ? a1 : a0;
            u32 p0 = cvt_pk(fmaxf(a[0], 0.f), fmaxf(a[1], 0.f));
            u32 p1 = cvt_pk(fmaxf(a[2], 0.f), fmaxf(a[3], 0.f));
            int colu = 16 * (2 * w + t) + 4 * gq;
            int byte = buf * 8192 + ((l15 * 512 + colu * 2) ^ ((l15 & 7) << 4));
            *(uint2*)(hbc + byte) = make_uint2(p0, p1);
        }
    };
    auto stage2 = [&](int m, int buf) {
        f32x4 accA = {b2v.x, b2v.y, b2v.z, b2v.w};
        f32x4 accB = {0.f, 0.f, 0.f, 0.f};
        #pragma unroll
        for (int c = 0; c < 4; ++c) {
            int byteA = buf * 8192 + ((l15 * 512 + (2 * c) * 64 + gq * 16) ^ ((l15 & 7) << 4));
            int byteB = buf * 8192 + ((l15 * 512 + (2 * c + 1) * 64 + gq * 16) ^ ((l15 & 7) << 4));
            const bf16x8 HA = *(const bf16x8*)(hbc + byteA);
            const bf16x8 HB = *(const bf16x8*)(hbc + byteB);
            accA = MFMA16(B2[2 * c], HA, accA);
            accB = MFMA16(B2[2 * c + 1], HB, accB);
        }
        float v0 = fmaxf(accA[0] + accB[0], 0.f), v1 = fmaxf(accA[1] + accB[1], 0.f);
        float v2 = fmaxf(accA[2] + accB[2], 0.f), v3 = fmaxf(accA[3] + accB[3], 0.f);
        int r = m * 16 + l15;
        *(uint2*)((char*)phibuf + r * 264 + (16 * w + 4 * gq) * 2) =
            make_uint2(cvt_pk(v0, v1), cvt_pk(v2, v3));
        float sp = v0 * sav.x + v1 * sav.y + v2 * sav.z + v3 * sav.w;
        sp += __shfl_xor(sp, 16, 64);
        sp += __shfl_xor(sp, 32, 64);
        if (gq == 0) spart[w][r] = sp;
    };

    // prologue: fill buffers 0,1
    {
        bf16x8 X0[5], X1[5];
        loadX(0, X0);
        loadX(1, X1);
        stage1(0, X0);
        stage1(1, X1);
    }
    __syncthreads();
    // interval 0: compute m=0,1; prefetch+stage1 m=2,3
    {
        bf16x8 X2[5], X3[5];
        loadX(2, X2);
        loadX(3, X3);
        stage2(0, 0);
        stage2(1, 1);
        stage1(2, X2);
        stage1(3, X3);
    }
    __syncthreads();
    // interval 1: compute m=2,3; prefetch+stage1 m=4 (reuse buf 0)
    {
        bf16x8 X4[5];
        loadX(4, X4);
        stage2(2, 2);
        stage2(3, 3);
        stage1(0, X4);
    }
    __syncthreads();
    // interval 2: compute m=4
    stage2(4, 0);
    __syncthreads();

    // ---- softmax over 5 objects per batch ----
    if (tid < 16) {
        const float s0c = sab[0];
        float ss[5];
        #pragma unroll
        for (int o = 0; o < 5; ++o) {
            float s = s0c;
            #pragma unroll
            for (int ww = 0; ww < 8; ++ww) s += spart[ww][tid * 5 + o];
            ss[o] = s;
        }
        float mx = fmaxf(fmaxf(fmaxf(ss[0], ss[1]), fmaxf(ss[2], ss[3])), ss[4]);
        float ex[5]; float den = 0.f;
        #pragma unroll
        for (int o = 0; o < 5; ++o) { ex[o] = __expf(ss[o] - mx); den += ex[o]; }
        float inv = 1.0f / den;
        #pragma unroll
        for (int o = 0; o < 5; ++o) awb[tid * 5 + o] = ex[o] * inv;
    }
    __syncthreads();

    // ---- pooling: 1024 u32 words (2 cols each) -> poolw (aliases dead hb) packed bf16 hi|lo ----
    #pragma unroll
    for (int rep = 0; rep < 2; ++rep) {
        int idx = rep * 512 + tid;       // < 1024
        int b = idx >> 6, cw = idx & 63; // u32 word = cols 2cw, 2cw+1
        float p0 = 0.f, p1 = 0.f;
        #pragma unroll
        for (int o = 0; o < 5; ++o) {
            u32 v = *(const u32*)((const char*)phibuf + (size_t)(b * 5 + o) * 264 + cw * 4);
            float a = awb[b * 5 + o];
            p0 = fmaf(a, blo(v), p0);
            p1 = fmaf(a, bhi(v), p1);
        }
        u16 h0 = bf16_rne(p0); u16 l0 = bf16_lo(p0, h0);
        u16 h1 = bf16_rne(p1); u16 l1 = bf16_lo(p1, h1);
        *(uint2*)(poolw + b * 132 + 2 * cw) =
            make_uint2((u32)h0 | ((u32)l0 << 16), (u32)h1 | ((u32)l1 << 16));
    }
    __syncthreads();   // phibuf dead after this point; rbuf may overwrite

    // ---- rho (swapped): A = pooled hi+lo, B = rhoW hi only ----
    {
        float4 rb0 = *(const float4*)(rhob + 16 * (2 * w + 0) + 4 * gq);
        float4 rb1 = *(const float4*)(rhob + 16 * (2 * w + 1) + 4 * gq);
        f32x4 acc0 = {rb0.x, rb0.y, rb0.z, rb0.w};
        f32x4 acc1 = {rb1.x, rb1.y, rb1.z, rb1.w};
        #pragma unroll
        for (int c = 0; c < 4; ++c) {
            uint4 q0 = *(const uint4*)(poolw + l15 * 132 + 32 * c + 8 * gq);
            uint4 q1 = *(const uint4*)(poolw + l15 * 132 + 32 * c + 8 * gq + 4);
            u32 ws[8] = {q0.x, q0.y, q0.z, q0.w, q1.x, q1.y, q1.z, q1.w};
            bf16x8 Ph, Pl;
            #pragma unroll
            for (int i = 0; i < 8; ++i) {
                Ph[i] = (short)(ws[i] & 0xffffu);
                Pl[i] = (short)(ws[i] >> 16);
            }
            #pragma unroll
            for (int t = 0; t < 2; ++t) {
                bf16x8 Bh = *(const bf16x8*)(BpR + (size_t)((c * 16 + 2 * w + t) * 2 + 0) * 512 + lane * 8);
                f32x4& a = t ? acc1 : acc0;
                a = MFMA16(Bh, Ph, a);
                a = MFMA16(Bh, Pl, a);
            }
        }
        #pragma unroll
        for (int t = 0; t < 2; ++t) {
            const f32x4& a = t ? acc1 : acc0;
            float4 v;
            v.x = fmaxf(a[0], 0.f); v.y = fmaxf(a[1], 0.f);
            v.z = fmaxf(a[2], 0.f); v.w = fmaxf(a[3], 0.f);
            *(float4*)(rbuf + l15 * 260 + 16 * (2 * w + t) + 4 * gq) = v;
        }
    }
    __syncthreads();

    // ---- heads split-k: 512 threads = 4 k-splits x (16 b x 8 q) ----
    {
        int s = tid >> 7, p = tid & 127;
        int b = p >> 3, q = p & 7;
        const float* rrow = rbuf + b * 260 + s * 64;
        const float* wcol = headWpk + s * 64 * 8 + q;
        float acc = 0.f;
        #pragma unroll 8
        for (int k = 0; k < 64; ++k)
            acc = fmaf(rrow[k], wcol[k * 8], acc);
        hpart[s * 128 + p] = acc;
    }
    __syncthreads();
    if (tid < 128) {
        int b = tid >> 3, q = tid & 7;
        float a = hpart[tid] + hpart[128 + tid] + hpart[256 + tid] + hpart[384 + tid];
        int bg = blockIdx.x * 16 + b;
        if (q < 4) {
            outp[(size_t)bg * 4 + q] = a + meanb[q];
        } else {
            float l = a + lsb[q - 4];
            outp[65536 + (size_t)bg * 4 + (q - 4)] = fminf(fmaxf(l, -20.0f), 2.0f);
        }
    }
}

extern "C" void kernel_launch(void* const* d_in, const int* in_sizes, int n_in,
                              void* d_out, int out_size, void* d_ws, size_t ws_size,
                              hipStream_t stream)
{
    const float* obs   = (const float*)d_in[0];
    const float* ag    = (const float*)d_in[1];
    const float* g     = (const float*)d_in[2];
    const float* mpW1  = (const float*)d_in[3];
    const float* mpb1  = (const float*)d_in[4];
    const float* mpW2  = (const float*)d_in[5];
    const float* mpb2  = (const float*)d_in[6];
    const float* eaW   = (const float*)d_in[7];
    const float* eab   = (const float*)d_in[8];
    const float* phW1  = (const float*)d_in[9];
    const float* phb1  = (const float*)d_in[10];
    const float* phW2  = (const float*)d_in[11];
    const float* phb2  = (const float*)d_in[12];
    const float* saW   = (const float*)d_in[13];
    const float* sab   = (const float*)d_in[14];
    const float* rhoW  = (const float*)d_in[15];
    const float* rhob  = (const float*)d_in[16];
    const float* meanW = (const float*)d_in[17];
    const float* meanb = (const float*)d_in[18];
    const float* lsW   = (const float*)d_in[19];
    const float* lsb   = (const float*)d_in[20];
    const int*   src   = (const int*)d_in[21];
    const int*   dst   = (const int*)d_in[22];
    const int*   inc   = (const int*)d_in[23];
    const int*   pred  = (const int*)d_in[24];

    // workspace layout (bytes), total ~37.3 MB:
    //  Ein  (u16 327680x16) : [0, 10485760)
    //  Nin  (u16 81920x160) : [10485760, 36700160)
    //  Bp1e (u16 8192)      : [36700160, +16384)
    //  Bp2e (u16 65536)     : [36716544, +131072)
    //  BpC1 (u16 81920)     : [36847616, +163840)
    //  BpC2 (u16 65536)     : [37011456, +131072)
    //  BpR  (u16 65536)     : [37142528, +131072)
    //  headWpk (f32 2048)   : [37273600, +8192)
    char* ws = (char*)d_ws;
    u16* Ein  = (u16*)(ws + 0);
    u16* Nin  = (u16*)(ws + 10485760ull);
    u16* Bp1e = (u16*)(ws + 36700160ull);
    u16* Bp2e = (u16*)(ws + 36716544ull);
    u16* BpC1 = (u16*)(ws + 36847616ull);
    u16* BpC2 = (u16*)(ws + 37011456ull);
    u16* BpR  = (u16*)(ws + 37142528ull);
    float* headWpk = (float*)(ws + 37273600ull);

    hipLaunchKernelGGL(PREP, dim3(2401), dim3(256), 0, stream,
                       mpW1, mpW2, phW1, phW2, rhoW, Bp1e, Bp2e, BpC1, BpC2, BpR,
                       obs, ag, g, src, dst, pred, Ein, meanW, lsW, headWpk);
    hipLaunchKernelGGL(GA, dim3(4096), dim3(512), 0, stream,
                       Ein, Bp1e, Bp2e, mpb1, mpb2, eaW, eab, inc, obs, Nin);
    hipLaunchKernelGGL(GB, dim3(1024), dim3(512), 0, stream,
                       Nin, BpC1, BpC2, BpR, phb1, phb2, saW, sab, rhob,
                       headWpk, meanb, lsb, (float*)d_out);
}

// Round 15
// 96.468 us; speedup vs baseline: 1.0911x; 1.0109x over previous
//
#include <hip/hip_runtime.h>
#include <cstdint>
#include <cstddef>

typedef unsigned short u16;
typedef unsigned int u32;
typedef __attribute__((ext_vector_type(8))) short bf16x8;
typedef __attribute__((ext_vector_type(4))) float f32x4;

#define MFMA16(A, B, C) __builtin_amdgcn_mfma_f32_16x16x32_bf16((A), (B), (C), 0, 0, 0)

__device__ __forceinline__ u16 bf16_rne(float x) {
    u32 u = __float_as_uint(x);
    u += 0x7fffu + ((u >> 16) & 1u);
    return (u16)(u >> 16);
}
__device__ __forceinline__ float bf2f(u16 h) { return __uint_as_float((u32)h << 16); }
__device__ __forceinline__ u16 bf16_lo(float x, u16 hi) { return bf16_rne(x - bf2f(hi)); }
__device__ __forceinline__ float blo(u32 u) { return __uint_as_float(u << 16); }
__device__ __forceinline__ float bhi(u32 u) { return __uint_as_float(u & 0xffff0000u); }
// packed f32x2 -> bf16x2 (lo<-a, hi<-b), RNE
__device__ __forceinline__ u32 cvt_pk(float a, float b) {
    u32 r;
    asm("v_cvt_pk_bf16_f32 %0, %1, %2" : "=v"(r) : "v"(a), "v"(b));
    return r;
}

// ================= prep bodies =================
// B-frag (16x16x32): lane l, elem i holds B[k = 8*(l>>4)+i][col = 16*tile + (l&15)]
// (same bytes as A-frag give A[row=l&15][k=8*(l>>4)+i] -> operand-swap transposes C)
__device__ __forceinline__ void PK_body(int tid,
    const float* __restrict__ mpW1, const float* __restrict__ mpW2,
    const float* __restrict__ phW1, const float* __restrict__ phW2,
    const float* __restrict__ rhoW,
    u16* __restrict__ Bp1e, u16* __restrict__ Bp2e,
    u16* __restrict__ BpC1, u16* __restrict__ BpC2, u16* __restrict__ BpR)
{
    if (tid < 8192) {
        // edge L1: 16 tiles x 512, 4-group trick [w_hi, w_hi, w_lo, w_lo]
        int t = tid >> 9, r = tid & 511;
        int l = r >> 3, i = r & 7, g = l >> 4, l15 = l & 15;
        float w = mpW1[i * 256 + 16 * t + l15];
        u16 h = bf16_rne(w);
        Bp1e[tid] = (g < 2) ? h : bf16_lo(w, h);
    } else if (tid < 73728) {
        // edge L2: [(c*8+n)*2+s][512] from mpW2 (256x128)
        int f = tid - 8192;
        int b5 = f >> 9, r = f & 511;
        int l = r >> 3, i = r & 7, g = l >> 4, l15 = l & 15;
        int s = b5 & 1, cn = b5 >> 1, c = cn >> 3, n = cn & 7;
        int kk = 32 * c + 8 * g + i;
        float w = mpW2[kk * 128 + 16 * n + l15];
        u16 h = bf16_rne(w);
        Bp2e[f] = s ? bf16_lo(w, h) : h;
    } else if (tid < 155648) {
        // node L1: [(c*2+s)*16+t][512] from phW1 (153x256), K perm: 0..24 direct, 25..31 zero, 32..159 -> 25..152
        int f = tid - 73728;
        int b5 = f >> 9, r = f & 511;
        int l = r >> 3, i = r & 7, g = l >> 4, l15 = l & 15;
        int t = b5 & 15, cs = b5 >> 4, s = cs & 1, c = cs >> 1;
        int kk = 32 * c + 8 * g + i;
        int kp = kk < 25 ? kk : (kk < 32 ? -1 : kk - 7);
        float w = (kp < 0) ? 0.0f : phW1[kp * 256 + 16 * t + l15];
        u16 h = bf16_rne(w);
        BpC1[f] = s ? bf16_lo(w, h) : h;
    } else if (tid < 221184) {
        // node L2: from phW2 (256x128)
        int f = tid - 155648;
        int b5 = f >> 9, r = f & 511;
        int l = r >> 3, i = r & 7, g = l >> 4, l15 = l & 15;
        int s = b5 & 1, cn = b5 >> 1, c = cn >> 3, n = cn & 7;
        int kk = 32 * c + 8 * g + i;
        float w = phW2[kk * 128 + 16 * n + l15];
        u16 h = bf16_rne(w);
        BpC2[f] = s ? bf16_lo(w, h) : h;
    } else {
        // rho: [(c*16+t)*2+s][512] from rhoW (128x256)
        int f = tid - 221184;
        int b5 = f >> 9, r = f & 511;
        int l = r >> 3, i = r & 7, g = l >> 4, l15 = l & 15;
        int s = b5 & 1, ct = b5 >> 1, c = ct >> 4, t = ct & 15;
        int kk = 32 * c + 8 * g + i;
        float w = rhoW[kk * 256 + 16 * t + l15];
        u16 h = bf16_rne(w);
        BpR[f] = s ? bf16_lo(w, h) : h;
    }
}

// Ein[row][16] bf16 : [x_hi(8) | x_lo(8)]  (GA reconstructs the 4-group via gq&1)
__device__ __forceinline__ void P1_body(int row,
    const float* __restrict__ obs, const float* __restrict__ ag, const float* __restrict__ g,
    const int* __restrict__ src, const int* __restrict__ dst, const int* __restrict__ pred,
    u16* __restrict__ Ein)
{
    int b = row / 20, p = row - b * 20;
    float inp[8];
    int i0 = pred[2 * p], i1 = pred[2 * p + 1];
    const float* gb = g + (size_t)b * 40;
    const float* ab = ag + (size_t)b * 40;
    inp[0] = gb[i0] - ab[i0];
    inp[1] = gb[i1] - ab[i1];
    int so = src[p], dd = dst[p];
    const float* ob = obs + (size_t)b * 85 + 10;
    inp[2] = ob[so * 15 + 0]; inp[3] = ob[so * 15 + 1]; inp[4] = ob[so * 15 + 2];
    inp[5] = ob[dd * 15 + 0]; inp[6] = ob[dd * 15 + 1]; inp[7] = ob[dd * 15 + 2];

    u32 wh[4], wl[4];
    #pragma unroll
    for (int k = 0; k < 4; ++k) {
        u16 h0 = bf16_rne(inp[2 * k]), h1 = bf16_rne(inp[2 * k + 1]);
        u16 l0 = bf16_lo(inp[2 * k], h0), l1 = bf16_lo(inp[2 * k + 1], h1);
        wh[k] = (u32)h0 | ((u32)h1 << 16);
        wl[k] = (u32)l0 | ((u32)l1 << 16);
    }
    uint4* d4 = (uint4*)(Ein + (size_t)row * 16);
    d4[0] = make_uint4(wh[0], wh[1], wh[2], wh[3]);
    d4[1] = make_uint4(wl[0], wl[1], wl[2], wl[3]);
}

// ================= PREP: PK + P1 + headWpk fused =================
__global__ __launch_bounds__(256) void PREP(
    const float* __restrict__ mpW1, const float* __restrict__ mpW2,
    const float* __restrict__ phW1, const float* __restrict__ phW2,
    const float* __restrict__ rhoW,
    u16* __restrict__ Bp1e, u16* __restrict__ Bp2e,
    u16* __restrict__ BpC1, u16* __restrict__ BpC2, u16* __restrict__ BpR,
    const float* __restrict__ obs, const float* __restrict__ ag, const float* __restrict__ g,
    const int* __restrict__ src, const int* __restrict__ dst, const int* __restrict__ pred,
    u16* __restrict__ Ein,
    const float* __restrict__ meanW, const float* __restrict__ lsW,
    float* __restrict__ headWpk)
{
    int bid = blockIdx.x;
    if (bid < 1120) {
        PK_body(bid * 256 + threadIdx.x, mpW1, mpW2, phW1, phW2, rhoW, Bp1e, Bp2e, BpC1, BpC2, BpR);
    } else if (bid < 2400) {
        P1_body((bid - 1120) * 256 + threadIdx.x, obs, ag, g, src, dst, pred, Ein);
    } else {
        // headWpk f32[256][8]: q<4 mean, q>=4 logstd
        int idx = threadIdx.x;
        #pragma unroll
        for (int r = 0; r < 8; ++r) {
            int f = r * 256 + idx;
            int k = f >> 3, q = f & 7;
            headWpk[f] = (q < 4) ? meanW[k * 4 + q] : lsW[k * 4 + (q - 4)];
        }
    }
}

// ================= GA: fused edge MLP + softmax-aggregate + node-input build =================
// 80 rows/block = 4 batches; 512 threads = 8 waves. Operand-swapped MFMAs, hi-only L2 weights.
// FULL phase-split: {stage1 x5 -> 5 h-buffers} barrier {stage2 x5} barrier -> 2 main-loop barriers.
__global__ __launch_bounds__(512) void GA(
    const u16* __restrict__ Ein, const u16* __restrict__ Bp1, const u16* __restrict__ Bp2,
    const float* __restrict__ b1, const float* __restrict__ b2,
    const float* __restrict__ eaW, const float* __restrict__ eab,
    const int* __restrict__ inc, const float* __restrict__ obs,
    u16* __restrict__ Nin)
{
    __shared__ u16 hb[5][16 * 256];     // 40960 B, 5 h-tile buffers, swizzled
    __shared__ u16 mpb[80 * 128];       // 20480 B, mp values, swizzled
    __shared__ float spart[8][80];      // per-wave e-score partials
    __shared__ float wbuf[80];
    __shared__ int rowb[80];
    __shared__ int incL[20];
    // total ~64.7 KB -> 2 blocks/CU

    const int tid = threadIdx.x;
    const int w = tid >> 6, lane = tid & 63;
    const int l15 = lane & 15, gq = lane >> 4;
    const int rowbase = blockIdx.x * 80;
    char* hbc = (char*)hb;
    char* mpc = (char*)mpb;

    if (tid < 20) incL[tid] = inc[tid];

    // stage-1 W-frags (tiles 2w, 2w+1; exact 4-group hi/lo) + per-col biases
    bf16x8 B1[2];
    float4 b1v[2];
    #pragma unroll
    for (int t = 0; t < 2; ++t) {
        B1[t] = *(const bf16x8*)(Bp1 + (size_t)(2 * w + t) * 512 + lane * 8);
        b1v[t] = *(const float4*)(b1 + 16 * (2 * w + t) + 4 * gq);
    }
    // stage-2 W-frags (tile n=w), hi only
    bf16x8 B2[8];
    #pragma unroll
    for (int c = 0; c < 8; ++c)
        B2[c] = *(const bf16x8*)(Bp2 + (size_t)((c * 8 + w) * 2) * 512 + lane * 8);
    const float4 b2v = *(const float4*)(b2 + 16 * w + 4 * gq);
    const float4 eav = *(const float4*)(eaW + 16 * w + 4 * gq);

    auto ldX = [&](int m) {
        return *(const bf16x8*)(Ein + (size_t)(rowbase + m * 16 + l15) * 16 + 8 * (gq & 1));
    };
    // ---- stage1: h[row=l15][col=16t+4gq+j] into hb[buf], b64 store ----
    auto stage1 = [&](int buf, const bf16x8& X) {
        #pragma unroll
        for (int t = 0; t < 2; ++t) {
            f32x4 acc = {b1v[t].x, b1v[t].y, b1v[t].z, b1v[t].w};
            acc = MFMA16(B1[t], X, acc);   // swapped: C[m=col][n=row]
            u32 p0 = cvt_pk(fmaxf(acc[0], 0.f), fmaxf(acc[1], 0.f));
            u32 p1 = cvt_pk(fmaxf(acc[2], 0.f), fmaxf(acc[3], 0.f));
            int colu = 16 * (2 * w + t) + 4 * gq;
            int byte = buf * 8192 + ((l15 * 512 + colu * 2) ^ ((l15 & 7) << 4));
            *(uint2*)(hbc + byte) = make_uint2(p0, p1);
        }
    };
    // ---- stage2(m): two indep acc chains; mp write + fused e-dot ----
    auto stage2 = [&](int m, int buf) {
        f32x4 accA = {b2v.x, b2v.y, b2v.z, b2v.w};
        f32x4 accB = {0.f, 0.f, 0.f, 0.f};
        #pragma unroll
        for (int c = 0; c < 4; ++c) {
            int byteA = buf * 8192 + ((l15 * 512 + (2 * c) * 64 + gq * 16) ^ ((l15 & 7) << 4));
            int byteB = buf * 8192 + ((l15 * 512 + (2 * c + 1) * 64 + gq * 16) ^ ((l15 & 7) << 4));
            const bf16x8 HA = *(const bf16x8*)(hbc + byteA);
            const bf16x8 HB = *(const bf16x8*)(hbc + byteB);
            accA = MFMA16(B2[2 * c], HA, accA);
            accB = MFMA16(B2[2 * c + 1], HB, accB);
        }
        float v0 = fmaxf(accA[0] + accB[0], 0.f), v1 = fmaxf(accA[1] + accB[1], 0.f);
        float v2 = fmaxf(accA[2] + accB[2], 0.f), v3 = fmaxf(accA[3] + accB[3], 0.f);
        float ep = v0 * eav.x + v1 * eav.y + v2 * eav.z + v3 * eav.w;
        ep += __shfl_xor(ep, 16, 64);
        ep += __shfl_xor(ep, 32, 64);
        if (gq == 0) spart[w][m * 16 + l15] = ep;
        u32 p0 = cvt_pk(v0, v1), p1 = cvt_pk(v2, v3);
        int r = m * 16 + l15;
        int byte2 = (r * 256 + (16 * w + 4 * gq) * 2) ^ ((r & 15) << 4);
        *(uint2*)(mpc + byte2) = make_uint2(p0, p1);
    };

    // phase 1: all five stage1s (10 MFMA + 5 global loads, no barriers)
    {
        bf16x8 X0 = ldX(0);
        bf16x8 X1 = ldX(1);
        bf16x8 X2 = ldX(2);
        bf16x8 X3 = ldX(3);
        bf16x8 X4 = ldX(4);
        stage1(0, X0);
        stage1(1, X1);
        stage1(2, X2);
        stage1(3, X3);
        stage1(4, X4);
    }
    __syncthreads();
    // phase 2: all five stage2s (40 MFMA, 5 independent chains, no barriers)
    stage2(0, 0);
    stage2(1, 1);
    stage2(2, 2);
    stage2(3, 3);
    stage2(4, 4);
    __syncthreads();

    // ---- softmax weights for 20 (batch,obj) pairs ∥ Nin cols 0..31 build on idle tail ----
    if (tid < 20) {
        int bl = tid / 5, o = tid - bl * 5;
        const float e0 = eab[0];
        int rr[4]; float ee[4];
        #pragma unroll
        for (int i = 0; i < 4; ++i) {
            rr[i] = bl * 20 + incL[o * 4 + i];
            float e = e0;
            #pragma unroll
            for (int ww = 0; ww < 8; ++ww) e += spart[ww][rr[i]];
            ee[i] = e;
        }
        float mx = fmaxf(fmaxf(ee[0], ee[1]), fmaxf(ee[2], ee[3]));
        float ex[4]; float den = 0.f;
        #pragma unroll
        for (int i = 0; i < 4; ++i) { ex[i] = __expf(ee[i] - mx); den += ex[i]; }
        float inv = 1.0f / den;
        #pragma unroll
        for (int i = 0; i < 4; ++i) {
            wbuf[tid * 4 + i] = ex[i] * inv;
            rowb[tid * 4 + i] = rr[i];
        }
    } else if (tid >= 320 && tid < 480) {
        // P2 work: 160 threads = 20 node rows x 8 quad-col groups
        int t2 = tid - 320;
        int p = t2 >> 3, q = t2 & 7;
        int bl = p / 5, o = p - bl * 5;
        const float* body = obs + (size_t)(blockIdx.x * 4 + bl) * 85;
        const float* op = body + 10 + o * 15;
        float v[4];
        #pragma unroll
        for (int jj = 0; jj < 4; ++jj) {
            int col = 4 * q + jj;
            v[jj] = (col < 10) ? body[col] : (col < 25) ? op[col - 10] : 0.0f;
        }
        int grow = blockIdx.x * 20 + p;
        *(uint2*)(Nin + (size_t)grow * 160 + 4 * q) =
            make_uint2(cvt_pk(v[0], v[1]), cvt_pk(v[2], v[3]));
    }
    __syncthreads();

    // ---- weighted gather -> Nin cols 32..159 ----
    if (tid < 320) {
        int p = tid >> 4, cb = tid & 15;
        float acc[8] = {0, 0, 0, 0, 0, 0, 0, 0};
        #pragma unroll
        for (int i = 0; i < 4; ++i) {
            int r = rowb[p * 4 + i];
            float wi = wbuf[p * 4 + i];
            int byte = (r * 256 + cb * 16) ^ ((r & 15) << 4);
            uint4 v = *(const uint4*)(mpc + byte);
            acc[0] = fmaf(wi, blo(v.x), acc[0]);
            acc[1] = fmaf(wi, bhi(v.x), acc[1]);
            acc[2] = fmaf(wi, blo(v.y), acc[2]);
            acc[3] = fmaf(wi, bhi(v.y), acc[3]);
            acc[4] = fmaf(wi, blo(v.z), acc[4]);
            acc[5] = fmaf(wi, bhi(v.z), acc[5]);
            acc[6] = fmaf(wi, blo(v.w), acc[6]);
            acc[7] = fmaf(wi, bhi(v.w), acc[7]);
        }
        uint4 ov;
        ov.x = cvt_pk(acc[0], acc[1]);
        ov.y = cvt_pk(acc[2], acc[3]);
        ov.z = cvt_pk(acc[4], acc[5]);
        ov.w = cvt_pk(acc[6], acc[7]);
        int grow = blockIdx.x * 20 + p;
        *(uint4*)(Nin + (size_t)grow * 160 + 32 + cb * 8) = ov;
    }
}

// ================= GB: fused node MLP + attn-pool + rho + heads -> out =================
// 80 rows/block = 16 batches; 512 threads = 8 waves.
// FULL phase-split: {stage1 x5 -> 5 h-buffers} barrier {stage2 x5} barrier.
__global__ __launch_bounds__(512) void GB(
    const u16* __restrict__ Nin, const u16* __restrict__ BpC1, const u16* __restrict__ BpC2,
    const u16* __restrict__ BpR,
    const float* __restrict__ b1, const float* __restrict__ b2,
    const float* __restrict__ saW, const float* __restrict__ sab,
    const float* __restrict__ rhob, const float* __restrict__ headWpk,
    const float* __restrict__ meanb, const float* __restrict__ lsb,
    float* __restrict__ outp)
{
    __shared__ u16 hb[5][16 * 256];      // 40960 B, 5 h-tile buffers; poolw aliases after main loop
    __shared__ u16 phibuf[80 * 132];     // 21120 B bf16 phi (stride 132); aliased as rbuf f32 stride 260
    __shared__ float spart[8][80];       // 2560 B; reused as hpart[512]
    __shared__ float awb[80];            // 320 B
    // total ~64.9 KB -> 2 blocks/CU

    const int tid = threadIdx.x;
    const int w = tid >> 6, lane = tid & 63;
    const int l15 = lane & 15, gq = lane >> 4;
    const int rowbase = blockIdx.x * 80;
    char* hbc = (char*)hb;
    float* rbuf = (float*)phibuf;        // alias, stride 260 f32 (16640 B <= 21120)
    float* hpart = (float*)spart;
    u32* poolw = (u32*)hb;               // alias over dead hb: 16x132 u32 = 8448 B <= 40960

    // stage-1 W-frags: 5 chunks x 2 tiles, hi only + per-col bias (RESIDENT)
    bf16x8 BC[5][2];
    float4 b1v[2];
    #pragma unroll
    for (int t = 0; t < 2; ++t) b1v[t] = *(const float4*)(b1 + 16 * (2 * w + t) + 4 * gq);
    #pragma unroll
    for (int c = 0; c < 5; ++c)
        #pragma unroll
        for (int t = 0; t < 2; ++t)
            BC[c][t] = *(const bf16x8*)(BpC1 + (size_t)((c * 2) * 16 + 2 * w + t) * 512 + lane * 8);
    // stage-2 W-frags, hi only (RESIDENT)
    bf16x8 B2[8];
    #pragma unroll
    for (int c = 0; c < 8; ++c)
        B2[c] = *(const bf16x8*)(BpC2 + (size_t)((c * 8 + w) * 2) * 512 + lane * 8);
    const float4 b2v = *(const float4*)(b2 + 16 * w + 4 * gq);
    const float4 sav = *(const float4*)(saW + 16 * w + 4 * gq);

    auto loadX = [&](int m, bf16x8* X) {
        #pragma unroll
        for (int c = 0; c < 5; ++c)
            X[c] = *(const bf16x8*)(Nin + (size_t)(rowbase + m * 16 + l15) * 160 + 32 * c + 8 * gq);
    };
    auto stage1 = [&](int buf, const bf16x8* X) {
        f32x4 a0 = {b1v[0].x, b1v[0].y, b1v[0].z, b1v[0].w};
        f32x4 a1 = {b1v[1].x, b1v[1].y, b1v[1].z, b1v[1].w};
        #pragma unroll
        for (int c = 0; c < 5; ++c) {
            a0 = MFMA16(BC[c][0], X[c], a0);
            a1 = MFMA16(BC[c][1], X[c], a1);
        }
        #pragma unroll
        for (int t = 0; t < 2; ++t) {
            const f32x4& a = t ? a1 : a0;
            u32 p0 = cvt_pk(fmaxf(a[0], 0.f), fmaxf(a[1], 0.f));
            u32 p1 = cvt_pk(fmaxf(a[2], 0.f), fmaxf(a[3], 0.f));
            int colu = 16 * (2 * w + t) + 4 * gq;
            int byte = buf * 8192 + ((l15 * 512 + colu * 2) ^ ((l15 & 7) << 4));
            *(uint2*)(hbc + byte) = make_uint2(p0, p1);
        }
    };
    auto stage2 = [&](int m, int buf) {
        f32x4 accA = {b2v.x, b2v.y, b2v.z, b2v.w};
        f32x4 accB = {0.f, 0.f, 0.f, 0.f};
        #pragma unroll
        for (int c = 0; c < 4; ++c) {
            int byteA = buf * 8192 + ((l15 * 512 + (2 * c) * 64 + gq * 16) ^ ((l15 & 7) << 4));
            int byteB = buf * 8192 + ((l15 * 512 + (2 * c + 1) * 64 + gq * 16) ^ ((l15 & 7) << 4));
            const bf16x8 HA = *(const bf16x8*)(hbc + byteA);
            const bf16x8 HB = *(const bf16x8*)(hbc + byteB);
            accA = MFMA16(B2[2 * c], HA, accA);
            accB = MFMA16(B2[2 * c + 1], HB, accB);
        }
        float v0 = fmaxf(accA[0] + accB[0], 0.f), v1 = fmaxf(accA[1] + accB[1], 0.f);
        float v2 = fmaxf(accA[2] + accB[2], 0.f), v3 = fmaxf(accA[3] + accB[3], 0.f);
        int r = m * 16 + l15;
        *(uint2*)((char*)phibuf + r * 264 + (16 * w + 4 * gq) * 2) =
            make_uint2(cvt_pk(v0, v1), cvt_pk(v2, v3));
        float sp = v0 * sav.x + v1 * sav.y + v2 * sav.z + v3 * sav.w;
        sp += __shfl_xor(sp, 16, 64);
        sp += __shfl_xor(sp, 32, 64);
        if (gq == 0) spart[w][r] = sp;
    };

    // phase 1: all five stage1s (50 MFMA + 25 global loads, no barriers)
    #pragma unroll
    for (int m = 0; m < 5; ++m) {
        bf16x8 X[5];
        loadX(m, X);
        stage1(m, X);
    }
    __syncthreads();
    // phase 2: all five stage2s (40 MFMA, 5 independent chains, no barriers)
    stage2(0, 0);
    stage2(1, 1);
    stage2(2, 2);
    stage2(3, 3);
    stage2(4, 4);
    __syncthreads();

    // ---- softmax over 5 objects per batch ----
    if (tid < 16) {
        const float s0c = sab[0];
        float ss[5];
        #pragma unroll
        for (int o = 0; o < 5; ++o) {
            float s = s0c;
            #pragma unroll
            for (int ww = 0; ww < 8; ++ww) s += spart[ww][tid * 5 + o];
            ss[o] = s;
        }
        float mx = fmaxf(fmaxf(fmaxf(ss[0], ss[1]), fmaxf(ss[2], ss[3])), ss[4]);
        float ex[5]; float den = 0.f;
        #pragma unroll
        for (int o = 0; o < 5; ++o) { ex[o] = __expf(ss[o] - mx); den += ex[o]; }
        float inv = 1.0f / den;
        #pragma unroll
        for (int o = 0; o < 5; ++o) awb[tid * 5 + o] = ex[o] * inv;
    }
    __syncthreads();

    // ---- pooling: 1024 u32 words (2 cols each) -> poolw (aliases dead hb) packed bf16 hi|lo ----
    #pragma unroll
    for (int rep = 0; rep < 2; ++rep) {
        int idx = rep * 512 + tid;       // < 1024
        int b = idx >> 6, cw = idx & 63; // u32 word = cols 2cw, 2cw+1
        float p0 = 0.f, p1 = 0.f;
        #pragma unroll
        for (int o = 0; o < 5; ++o) {
            u32 v = *(const u32*)((const char*)phibuf + (size_t)(b * 5 + o) * 264 + cw * 4);
            float a = awb[b * 5 + o];
            p0 = fmaf(a, blo(v), p0);
            p1 = fmaf(a, bhi(v), p1);
        }
        u16 h0 = bf16_rne(p0); u16 l0 = bf16_lo(p0, h0);
        u16 h1 = bf16_rne(p1); u16 l1 = bf16_lo(p1, h1);
        *(uint2*)(poolw + b * 132 + 2 * cw) =
            make_uint2((u32)h0 | ((u32)l0 << 16), (u32)h1 | ((u32)l1 << 16));
    }
    __syncthreads();   // phibuf dead after this point; rbuf may overwrite

    // ---- rho (swapped): A = pooled hi+lo, B = rhoW hi only ----
    {
        float4 rb0 = *(const float4*)(rhob + 16 * (2 * w + 0) + 4 * gq);
        float4 rb1 = *(const float4*)(rhob + 16 * (2 * w + 1) + 4 * gq);
        f32x4 acc0 = {rb0.x, rb0.y, rb0.z, rb0.w};
        f32x4 acc1 = {rb1.x, rb1.y, rb1.z, rb1.w};
        #pragma unroll
        for (int c = 0; c < 4; ++c) {
            uint4 q0 = *(const uint4*)(poolw + l15 * 132 + 32 * c + 8 * gq);
            uint4 q1 = *(const uint4*)(poolw + l15 * 132 + 32 * c + 8 * gq + 4);
            u32 ws[8] = {q0.x, q0.y, q0.z, q0.w, q1.x, q1.y, q1.z, q1.w};
            bf16x8 Ph, Pl;
            #pragma unroll
            for (int i = 0; i < 8; ++i) {
                Ph[i] = (short)(ws[i] & 0xffffu);
                Pl[i] = (short)(ws[i] >> 16);
            }
            #pragma unroll
            for (int t = 0; t < 2; ++t) {
                bf16x8 Bh = *(const bf16x8*)(BpR + (size_t)((c * 16 + 2 * w + t) * 2 + 0) * 512 + lane * 8);
                f32x4& a = t ? acc1 : acc0;
                a = MFMA16(Bh, Ph, a);
                a = MFMA16(Bh, Pl, a);
            }
        }
        #pragma unroll
        for (int t = 0; t < 2; ++t) {
            const f32x4& a = t ? acc1 : acc0;
            float4 v;
            v.x = fmaxf(a[0], 0.f); v.y = fmaxf(a[1], 0.f);
            v.z = fmaxf(a[2], 0.f); v.w = fmaxf(a[3], 0.f);
            *(float4*)(rbuf + l15 * 260 + 16 * (2 * w + t) + 4 * gq) = v;
        }
    }
    __syncthreads();

    // ---- heads split-k: 512 threads = 4 k-splits x (16 b x 8 q) ----
    {
        int s = tid >> 7, p = tid & 127;
        int b = p >> 3, q = p & 7;
        const float* rrow = rbuf + b * 260 + s * 64;
        const float* wcol = headWpk + s * 64 * 8 + q;
        float acc = 0.f;
        #pragma unroll 8
        for (int k = 0; k < 64; ++k)
            acc = fmaf(rrow[k], wcol[k * 8], acc);
        hpart[s * 128 + p] = acc;
    }
    __syncthreads();
    if (tid < 128) {
        int b = tid >> 3, q = tid & 7;
        float a = hpart[tid] + hpart[128 + tid] + hpart[256 + tid] + hpart[384 + tid];
        int bg = blockIdx.x * 16 + b;
        if (q < 4) {
            outp[(size_t)bg * 4 + q] = a + meanb[q];
        } else {
            float l = a + lsb[q - 4];
            outp[65536 + (size_t)bg * 4 + (q - 4)] = fminf(fmaxf(l, -20.0f), 2.0f);
        }
    }
}

extern "C" void kernel_launch(void* const* d_in, const int* in_sizes, int n_in,
                              void* d_out, int out_size, void* d_ws, size_t ws_size,
                              hipStream_t stream)
{
    const float* obs   = (const float*)d_in[0];
    const float* ag    = (const float*)d_in[1];
    const float* g     = (const float*)d_in[2];
    const float* mpW1  = (const float*)d_in[3];
    const float* mpb1  = (const float*)d_in[4];
    const float* mpW2  = (const float*)d_in[5];
    const float* mpb2  = (const float*)d_in[6];
    const float* eaW   = (const float*)d_in[7];
    const float* eab   = (const float*)d_in[8];
    const float* phW1  = (const float*)d_in[9];
    const float* phb1  = (const float*)d_in[10];
    const float* phW2  = (const float*)d_in[11];
    const float* phb2  = (const float*)d_in[12];
    const float* saW   = (const float*)d_in[13];
    const float* sab   = (const float*)d_in[14];
    const float* rhoW  = (const float*)d_in[15];
    const float* rhob  = (const float*)d_in[16];
    const float* meanW = (const float*)d_in[17];
    const float* meanb = (const float*)d_in[18];
    const float* lsW   = (const float*)d_in[19];
    const float* lsb   = (const float*)d_in[20];
    const int*   src   = (const int*)d_in[21];
    const int*   dst   = (const int*)d_in[22];
    const int*   inc   = (const int*)d_in[23];
    const int*   pred  = (const int*)d_in[24];

    // workspace layout (bytes), total ~37.3 MB:
    //  Ein  (u16 327680x16) : [0, 10485760)
    //  Nin  (u16 81920x160) : [10485760, 36700160)
    //  Bp1e (u16 8192)      : [36700160, +16384)
    //  Bp2e (u16 65536)     : [36716544, +131072)
    //  BpC1 (u16 81920)     : [36847616, +163840)
    //  BpC2 (u16 65536)     : [37011456, +131072)
    //  BpR  (u16 65536)     : [37142528, +131072)
    //  headWpk (f32 2048)   : [37273600, +8192)
    char* ws = (char*)d_ws;
    u16* Ein  = (u16*)(ws + 0);
    u16* Nin  = (u16*)(ws + 10485760ull);
    u16* Bp1e = (u16*)(ws + 36700160ull);
    u16* Bp2e = (u16*)(ws + 36716544ull);
    u16* BpC1 = (u16*)(ws + 36847616ull);
    u16* BpC2 = (u16*)(ws + 37011456ull);
    u16* BpR  = (u16*)(ws + 37142528ull);
    float* headWpk = (float*)(ws + 37273600ull);

    hipLaunchKernelGGL(PREP, dim3(2401), dim3(256), 0, stream,
                       mpW1, mpW2, phW1, phW2, rhoW, Bp1e, Bp2e, BpC1, BpC2, BpR,
                       obs, ag, g, src, dst, pred, Ein, meanW, lsW, headWpk);
    hipLaunchKernelGGL(GA, dim3(4096), dim3(512), 0, stream,
                       Ein, Bp1e, Bp2e, mpb1, mpb2, eaW, eab, inc, obs, Nin);
    hipLaunchKernelGGL(GB, dim3(1024), dim3(512), 0, stream,
                       Nin, BpC1, BpC2, BpR, phb1, phb2, saW, sab, rhob,
                       headWpk, meanb, lsb, (float*)d_out);
}